// Round 2
// baseline (5003.281 us; speedup 1.0000x reference)
//
#include <hip/hip_runtime.h>
#include <hip/hip_bf16.h>
#include <cstdio>

#define N_P   65536
#define N_E   524288
#define RIG_  4096
#define NF_   128

typedef __hip_bfloat16 bf16;

// ---------- helpers ----------
__device__ __forceinline__ float attr2_elem(const float* __restrict__ state,
                                            const float* __restrict__ attr,
                                            const float* __restrict__ cent,
                                            int p, int j) {
    // attr2 = [attr(3), offset(6)] ; offset = (p<RIG) ? state-centroid : 0
    if (j < 3) return attr[p * 3 + j];
    int k = j - 3;
    return (p < RIG_) ? (state[p * 6 + k] - cent[k]) : 0.0f;
}

// ---------- 1. rigid centroid over state[:RIG] (6 dims) ----------
__global__ __launch_bounds__(256) void k_centroid(const float* __restrict__ state,
                                                  float* __restrict__ cent) {
    int d = blockIdx.x;              // 0..5
    __shared__ float red[256];
    float s = 0.f;
    for (int r = threadIdx.x; r < RIG_; r += 256) s += state[r * 6 + d];
    red[threadIdx.x] = s; __syncthreads();
    for (int o = 128; o > 0; o >>= 1) {
        if (threadIdx.x < o) red[threadIdx.x] += red[threadIdx.x + o];
        __syncthreads();
    }
    if (threadIdx.x == 0) cent[d] = red[0] / (float)RIG_;
}

// ---------- 2. particle encoder: [attr2, state](15) -> 128 -> 128 ----------
__global__ __launch_bounds__(128) void k_particle_enc(
        const float* __restrict__ state, const float* __restrict__ attr,
        const float* __restrict__ cent,
        const float* __restrict__ w0, const float* __restrict__ b0,
        const float* __restrict__ w1, const float* __restrict__ b1,
        float* __restrict__ pe_out) {
    __shared__ float in_s[8][16];   // 15 used, pad to 16
    __shared__ float h_s[8][128];
    int t = threadIdx.x;
    int base = blockIdx.x * 8;
    if (t < 120) {
        int r = t / 15, c = t % 15;
        int p = base + r;
        float v;
        if (c < 3)      v = attr[p * 3 + c];
        else if (c < 9) v = (p < RIG_) ? (state[p * 6 + (c - 3)] - cent[c - 3]) : 0.0f;
        else            v = state[p * 6 + (c - 9)];
        in_s[r][c] = v;
    }
    __syncthreads();
    // layer 1
    float wreg[15];
    #pragma unroll
    for (int k = 0; k < 15; k++) wreg[k] = w0[t * 15 + k];
    float bb = b0[t];
    #pragma unroll
    for (int r = 0; r < 8; r++) {
        float a = bb;
        #pragma unroll
        for (int k = 0; k < 15; k++) a += wreg[k] * in_s[r][k];
        h_s[r][t] = fmaxf(a, 0.f);
    }
    __syncthreads();
    // layer 2 (128 wide, float4)
    float acc[8];
    float b1v = b1[t];
    #pragma unroll
    for (int r = 0; r < 8; r++) acc[r] = b1v;
    for (int k = 0; k < 128; k += 4) {
        const float4 wv = *(const float4*)(w1 + (size_t)t * 128 + k);
        #pragma unroll
        for (int r = 0; r < 8; r++) {
            const float4 xv = *(const float4*)(&h_s[r][k]);
            acc[r] += wv.x * xv.x + wv.y * xv.y + wv.z * xv.z + wv.w * xv.w;
        }
    }
    #pragma unroll
    for (int r = 0; r < 8; r++) pe_out[(size_t)(base + r) * 128 + t] = fmaxf(acc[r], 0.f);
}

// ---------- 3. relation encoder: rel_in(31) -> 128 -> 128 -> 128 (bf16 out) ----------
__global__ __launch_bounds__(128) void k_rel_enc(
        const float* __restrict__ state, const float* __restrict__ attr,
        const float* __restrict__ Ra,
        const int* __restrict__ recv, const int* __restrict__ send,
        const float* __restrict__ cent,
        const float* __restrict__ w0, const float* __restrict__ b0,
        const float* __restrict__ w1, const float* __restrict__ b1,
        const float* __restrict__ w2, const float* __restrict__ b2,
        bf16* __restrict__ re_out) {
    __shared__ float in_s[8][32];   // 31 used
    __shared__ float h_s[8][128];
    __shared__ float g_s[8][128];
    int t = threadIdx.x;
    long base = (long)blockIdx.x * 8;
    for (int it = t; it < 8 * 31; it += 128) {
        int r = it / 31, c = it % 31;
        long e = base + r;
        float v;
        if (c < 9)       { int p = recv[e]; v = attr2_elem(state, attr, cent, p, c); }
        else if (c < 18) { int p = send[e]; v = attr2_elem(state, attr, cent, p, c - 9); }
        else if (c < 24) { int p = recv[e]; v = state[p * 6 + (c - 18)]; }
        else if (c < 30) { int p = send[e]; v = state[p * 6 + (c - 24)]; }
        else             v = Ra[e];
        in_s[r][c] = v;
    }
    __syncthreads();
    // layer 1 (31 wide)
    float wreg[31];
    #pragma unroll
    for (int k = 0; k < 31; k++) wreg[k] = w0[t * 31 + k];
    float bb = b0[t];
    #pragma unroll
    for (int r = 0; r < 8; r++) {
        float a = bb;
        #pragma unroll
        for (int k = 0; k < 31; k++) a += wreg[k] * in_s[r][k];
        h_s[r][t] = fmaxf(a, 0.f);
    }
    __syncthreads();
    // layer 2
    float acc[8];
    bb = b1[t];
    #pragma unroll
    for (int r = 0; r < 8; r++) acc[r] = bb;
    for (int k = 0; k < 128; k += 4) {
        const float4 wv = *(const float4*)(w1 + (size_t)t * 128 + k);
        #pragma unroll
        for (int r = 0; r < 8; r++) {
            const float4 xv = *(const float4*)(&h_s[r][k]);
            acc[r] += wv.x * xv.x + wv.y * xv.y + wv.z * xv.z + wv.w * xv.w;
        }
    }
    #pragma unroll
    for (int r = 0; r < 8; r++) g_s[r][t] = fmaxf(acc[r], 0.f);
    __syncthreads();
    // layer 3
    bb = b2[t];
    #pragma unroll
    for (int r = 0; r < 8; r++) acc[r] = bb;
    for (int k = 0; k < 128; k += 4) {
        const float4 wv = *(const float4*)(w2 + (size_t)t * 128 + k);
        #pragma unroll
        for (int r = 0; r < 8; r++) {
            const float4 xv = *(const float4*)(&g_s[r][k]);
            acc[r] += wv.x * xv.x + wv.y * xv.y + wv.z * xv.z + wv.w * xv.w;
        }
    }
    #pragma unroll
    for (int r = 0; r < 8; r++)
        re_out[(base + r) * 128 + t] = __float2bfloat16(fmaxf(acc[r], 0.f));
}

// ---------- 4. propagation edge: [re, eff[recv], eff[send]](384) -> 128, scatter-add ----------
__global__ __launch_bounds__(128) void k_prop_edge(
        const bf16* __restrict__ re, const float* __restrict__ eff,
        const int* __restrict__ recv, const int* __restrict__ send,
        const float* __restrict__ w, const float* __restrict__ b,
        float* __restrict__ agg) {
    __shared__ float in_s[8][384];
    __shared__ int rv_s[8], sv_s[8];
    int t = threadIdx.x;
    long base = (long)blockIdx.x * 8;
    if (t < 8) { rv_s[t] = recv[base + t]; sv_s[t] = send[base + t]; }
    __syncthreads();
    #pragma unroll
    for (int r = 0; r < 8; r++) {
        in_s[r][t]       = __bfloat162float(re[(base + r) * 128 + t]);
        in_s[r][128 + t] = eff[(size_t)rv_s[r] * 128 + t];
        in_s[r][256 + t] = eff[(size_t)sv_s[r] * 128 + t];
    }
    __syncthreads();
    float acc[8];
    float bb = b[t];
    #pragma unroll
    for (int r = 0; r < 8; r++) acc[r] = bb;
    for (int k = 0; k < 384; k += 4) {
        const float4 wv = *(const float4*)(w + (size_t)t * 384 + k);
        #pragma unroll
        for (int r = 0; r < 8; r++) {
            const float4 xv = *(const float4*)(&in_s[r][k]);
            acc[r] += wv.x * xv.x + wv.y * xv.y + wv.z * xv.z + wv.w * xv.w;
        }
    }
    #pragma unroll
    for (int r = 0; r < 8; r++) {
        atomicAdd(&agg[(size_t)rv_s[r] * 128 + t], fmaxf(acc[r], 0.f));
    }
}

// ---------- 5. node update: [pe, agg](256) -> 128 ----------
__global__ __launch_bounds__(128) void k_node(
        const float* __restrict__ pe, const float* __restrict__ agg,
        const float* __restrict__ w, const float* __restrict__ b,
        float* __restrict__ eff) {
    __shared__ float in_s[8][256];
    int t = threadIdx.x;
    long base = (long)blockIdx.x * 8;
    #pragma unroll
    for (int r = 0; r < 8; r++) {
        in_s[r][t]       = pe[(base + r) * 128 + t];
        in_s[r][128 + t] = agg[(base + r) * 128 + t];
    }
    __syncthreads();
    float acc[8];
    float bb = b[t];
    #pragma unroll
    for (int r = 0; r < 8; r++) acc[r] = bb;
    for (int k = 0; k < 256; k += 4) {
        const float4 wv = *(const float4*)(w + (size_t)t * 256 + k);
        #pragma unroll
        for (int r = 0; r < 8; r++) {
            const float4 xv = *(const float4*)(&in_s[r][k]);
            acc[r] += wv.x * xv.x + wv.y * xv.y + wv.z * xv.z + wv.w * xv.w;
        }
    }
    #pragma unroll
    for (int r = 0; r < 8; r++) eff[(base + r) * 128 + t] = fmaxf(acc[r], 0.f);
}

// ---------- 6. pooled mean over effect[:RIG] ----------
__global__ __launch_bounds__(256) void k_pool(const float* __restrict__ eff,
                                              float* __restrict__ pooled) {
    int f = blockIdx.x;              // feature 0..127
    __shared__ float red[256];
    float s = 0.f;
    for (int r = threadIdx.x; r < RIG_; r += 256) s += eff[(size_t)r * 128 + f];
    red[threadIdx.x] = s; __syncthreads();
    for (int o = 128; o > 0; o >>= 1) {
        if (threadIdx.x < o) red[threadIdx.x] += red[threadIdx.x + o];
        __syncthreads();
    }
    if (threadIdx.x == 0) pooled[f] = red[0] / (float)RIG_;
}

// ---------- 7. rigid head: 128 -> 128 -> 128 -> 7 ; build R,b ----------
__global__ __launch_bounds__(128) void k_rigid_head(
        const float* __restrict__ pooled,
        const float* __restrict__ w0, const float* __restrict__ b0,
        const float* __restrict__ w1, const float* __restrict__ b1,
        const float* __restrict__ w2, const float* __restrict__ b2,
        float* __restrict__ rig /* R[9], trans[3] */) {
    __shared__ float pl[128], ha[128], hb[128], tv[7];
    int t = threadIdx.x;
    pl[t] = pooled[t];
    __syncthreads();
    float a = b0[t];
    for (int k = 0; k < 128; k++) a += w0[t * 128 + k] * pl[k];
    ha[t] = fmaxf(a, 0.f);
    __syncthreads();
    a = b1[t];
    for (int k = 0; k < 128; k++) a += w1[t * 128 + k] * ha[k];
    hb[t] = fmaxf(a, 0.f);
    __syncthreads();
    if (t < 7) {
        float s = b2[t];
        for (int k = 0; k < 128; k++) s += w2[t * 128 + k] * hb[k];
        tv[t] = s;
    }
    __syncthreads();
    if (t == 0) {
        float w = tv[0], x = tv[1], y = tv[2], z = tv[3];
        float n = sqrtf(w * w + x * x + y * y + z * z);
        w /= n; x /= n; y /= n; z /= n;
        rig[0] = 1.f - 2.f * (y * y + z * z); rig[1] = 2.f * (x * y + z * w); rig[2] = 2.f * (x * z - y * w);
        rig[3] = 2.f * (x * y - z * w); rig[4] = 1.f - 2.f * (x * x + z * z); rig[5] = 2.f * (y * z + x * w);
        rig[6] = 2.f * (x * z + y * w); rig[7] = 2.f * (y * z - x * w); rig[8] = 1.f - 2.f * (x * x + y * y);
        rig[9] = tv[4]; rig[10] = tv[5]; rig[11] = tv[6];
    }
}

// ---------- 8a. rigid output ----------
__global__ __launch_bounds__(256) void k_rigid_out(
        const float* __restrict__ state, const float* __restrict__ cent,
        const float* __restrict__ rig, float* __restrict__ out) {
    int i = blockIdx.x * 256 + threadIdx.x;
    if (i >= RIG_) return;
    float p0[3], d[3];
    #pragma unroll
    for (int k = 0; k < 3; k++) { p0[k] = state[i * 6 + k]; d[k] = p0[k] - cent[k]; }
    #pragma unroll
    for (int j = 0; j < 3; j++) {
        float p1 = rig[0 * 3 + j] * d[0] + rig[1 * 3 + j] * d[1] + rig[2 * 3 + j] * d[2]
                 + rig[9 + j] + cent[j];
        out[i * 3 + j] = (p1 - p0[j]) * 60.0f;   // /DT, std_v=1, mean_v=0
    }
}

// ---------- 8b. fluid output: 128 -> 128 -> 128 -> 3 ----------
__global__ __launch_bounds__(128) void k_fluid(
        const float* __restrict__ eff,
        const float* __restrict__ w0, const float* __restrict__ b0,
        const float* __restrict__ w1, const float* __restrict__ b1,
        const float* __restrict__ w2, const float* __restrict__ b2,
        float* __restrict__ out) {
    __shared__ float a_s[8][128], b_s[8][128];
    int t = threadIdx.x;
    long base = RIG_ + (long)blockIdx.x * 8;
    #pragma unroll
    for (int r = 0; r < 8; r++) a_s[r][t] = eff[(base + r) * 128 + t];
    __syncthreads();
    float acc[8];
    float bb = b0[t];
    #pragma unroll
    for (int r = 0; r < 8; r++) acc[r] = bb;
    for (int k = 0; k < 128; k += 4) {
        const float4 wv = *(const float4*)(w0 + (size_t)t * 128 + k);
        #pragma unroll
        for (int r = 0; r < 8; r++) {
            const float4 xv = *(const float4*)(&a_s[r][k]);
            acc[r] += wv.x * xv.x + wv.y * xv.y + wv.z * xv.z + wv.w * xv.w;
        }
    }
    #pragma unroll
    for (int r = 0; r < 8; r++) b_s[r][t] = fmaxf(acc[r], 0.f);
    __syncthreads();
    bb = b1[t];
    #pragma unroll
    for (int r = 0; r < 8; r++) acc[r] = bb;
    for (int k = 0; k < 128; k += 4) {
        const float4 wv = *(const float4*)(w1 + (size_t)t * 128 + k);
        #pragma unroll
        for (int r = 0; r < 8; r++) {
            const float4 xv = *(const float4*)(&b_s[r][k]);
            acc[r] += wv.x * xv.x + wv.y * xv.y + wv.z * xv.z + wv.w * xv.w;
        }
    }
    __syncthreads();   // all reads of a_s (layer1) done; safe to overwrite
    #pragma unroll
    for (int r = 0; r < 8; r++) a_s[r][t] = fmaxf(acc[r], 0.f);
    __syncthreads();
    if (t < 24) {
        int r = t / 3, o = t % 3;
        float s = b2[o];
        for (int k = 0; k < 128; k++) s += w2[o * 128 + k] * a_s[r][k];
        out[(base + r) * 3 + o] = s;
    }
}

extern "C" void kernel_launch(void* const* d_in, const int* in_sizes, int n_in,
                              void* d_out, int out_size, void* d_ws, size_t ws_size,
                              hipStream_t stream) {
    const float* state = (const float*)d_in[0];
    const float* attr  = (const float*)d_in[1];
    const float* Ra    = (const float*)d_in[2];
    const int*   recv  = (const int*)d_in[3];
    const int*   send  = (const int*)d_in[4];
    const float* pe_w0 = (const float*)d_in[5];  const float* pe_b0 = (const float*)d_in[6];
    const float* pe_w1 = (const float*)d_in[7];  const float* pe_b1 = (const float*)d_in[8];
    const float* re_w0 = (const float*)d_in[9];  const float* re_b0 = (const float*)d_in[10];
    const float* re_w1 = (const float*)d_in[11]; const float* re_b1 = (const float*)d_in[12];
    const float* re_w2 = (const float*)d_in[13]; const float* re_b2 = (const float*)d_in[14];
    const float* rp_w  = (const float*)d_in[15]; const float* rp_b  = (const float*)d_in[16];
    const float* pp_w  = (const float*)d_in[17]; const float* pp_b  = (const float*)d_in[18];
    const float* rg_w0 = (const float*)d_in[19]; const float* rg_b0 = (const float*)d_in[20];
    const float* rg_w1 = (const float*)d_in[21]; const float* rg_b1 = (const float*)d_in[22];
    const float* rg_w2 = (const float*)d_in[23]; const float* rg_b2 = (const float*)d_in[24];
    const float* fl_w0 = (const float*)d_in[25]; const float* fl_b0 = (const float*)d_in[26];
    const float* fl_w1 = (const float*)d_in[27]; const float* fl_b1 = (const float*)d_in[28];
    const float* fl_w2 = (const float*)d_in[29]; const float* fl_b2 = (const float*)d_in[30];
    float* out = (float*)d_out;

    // workspace layout: f32 node buffers first, then bf16 relation_encode
    float* pe   = (float*)d_ws;                   // N*128 f32   (33.5 MB)
    float* eff  = pe  + (size_t)N_P * 128;        // N*128 f32
    float* agg  = eff + (size_t)N_P * 128;        // N*128 f32
    bf16*  re   = (bf16*)(agg + (size_t)N_P * 128); // E*128 bf16 (134.2 MB)
    float* cent = (float*)(re + (size_t)N_E * 128); // 6 (pad 8)
    float* pooled = cent + 8;                     // 128
    float* rig    = pooled + 128;                 // 12

    size_t need = (size_t)N_P * 128 * 3 * sizeof(float)
                + (size_t)N_E * 128 * sizeof(bf16)
                + 160 * sizeof(float);
    if (ws_size < need) {
        fprintf(stderr, "kernel_launch: ws_size %zu < needed %zu\n", ws_size, need);
        return;
    }

    // 1. centroid
    k_centroid<<<6, 256, 0, stream>>>(state, cent);
    // 2. particle encoder
    k_particle_enc<<<N_P / 8, 128, 0, stream>>>(state, attr, cent, pe_w0, pe_b0, pe_w1, pe_b1, pe);
    // 3. relation encoder
    k_rel_enc<<<N_E / 8, 128, 0, stream>>>(state, attr, Ra, recv, send, cent,
                                           re_w0, re_b0, re_w1, re_b1, re_w2, re_b2, re);
    // init effect = 0
    hipMemsetAsync(eff, 0, (size_t)N_P * 128 * sizeof(float), stream);
    // 4/5. propagation steps
    for (int step = 0; step < 2; step++) {
        hipMemsetAsync(agg, 0, (size_t)N_P * 128 * sizeof(float), stream);
        k_prop_edge<<<N_E / 8, 128, 0, stream>>>(re, eff, recv, send, rp_w, rp_b, agg);
        k_node<<<N_P / 8, 128, 0, stream>>>(pe, agg, pp_w, pp_b, eff);
    }
    // 6. pooled mean
    k_pool<<<128, 256, 0, stream>>>(eff, pooled);
    // 7. rigid head
    k_rigid_head<<<1, 128, 0, stream>>>(pooled, rg_w0, rg_b0, rg_w1, rg_b1, rg_w2, rg_b2, rig);
    // 8a. rigid output
    k_rigid_out<<<(RIG_ + 255) / 256, 256, 0, stream>>>(state, cent, rig, out);
    // 8b. fluid output
    k_fluid<<<(N_P - RIG_) / 8, 128, 0, stream>>>(eff, fl_w0, fl_b0, fl_w1, fl_b1, fl_w2, fl_b2, out);
}

// Round 3
// 1941.546 us; speedup vs baseline: 2.5770x; 2.5770x over previous
//
#include <hip/hip_runtime.h>
#include <hip/hip_bf16.h>
#include <cstdio>

#define N_P   65536
#define N_E   524288
#define RIG_  4096
#define NF_   128

typedef __attribute__((ext_vector_type(8))) short bf16x8;
typedef __attribute__((ext_vector_type(4))) float f32x4;

// ---------- helpers ----------
__device__ __forceinline__ float attr2_elem(const float* __restrict__ state,
                                            const float* __restrict__ attr,
                                            const float* __restrict__ cent,
                                            int p, int j) {
    if (j < 3) return attr[p * 3 + j];
    int k = j - 3;
    return (p < RIG_) ? (state[p * 6 + k] - cent[k]) : 0.0f;
}

__device__ __forceinline__ unsigned short f2b(float x) {
    __hip_bfloat16 h = __float2bfloat16(x);
    return *(unsigned short*)&h;
}
__device__ __forceinline__ unsigned pk2(float x, float y) {
    return (unsigned)f2b(x) | ((unsigned)f2b(y) << 16);
}

// ---------- 0. weight conversion f32 -> bf16 ----------
__global__ __launch_bounds__(256) void k_cvt(const float* __restrict__ src,
                                             unsigned short* __restrict__ dst, int n) {
    int i = blockIdx.x * 256 + threadIdx.x;
    if (i < n) dst[i] = f2b(src[i]);
}
// re_w0 [128][31] -> padded [128][32], col 31 = 0
__global__ __launch_bounds__(256) void k_cvt_w0pad(const float* __restrict__ src,
                                                   unsigned short* __restrict__ dst) {
    int i = blockIdx.x * 256 + threadIdx.x;
    if (i < 128 * 32) {
        int r = i >> 5, c = i & 31;
        dst[i] = (c < 31) ? f2b(src[r * 31 + c]) : 0;
    }
}

// ---------- 1. rigid centroid over state[:RIG] (6 dims) ----------
__global__ __launch_bounds__(256) void k_centroid(const float* __restrict__ state,
                                                  float* __restrict__ cent) {
    int d = blockIdx.x;
    __shared__ float red[256];
    float s = 0.f;
    for (int r = threadIdx.x; r < RIG_; r += 256) s += state[r * 6 + d];
    red[threadIdx.x] = s; __syncthreads();
    for (int o = 128; o > 0; o >>= 1) {
        if (threadIdx.x < o) red[threadIdx.x] += red[threadIdx.x + o];
        __syncthreads();
    }
    if (threadIdx.x == 0) cent[d] = red[0] / (float)RIG_;
}

// ---------- 2. particle encoder: [attr2, state](15) -> 128 -> 128 (f32) ----------
__global__ __launch_bounds__(128) void k_particle_enc(
        const float* __restrict__ state, const float* __restrict__ attr,
        const float* __restrict__ cent,
        const float* __restrict__ w0, const float* __restrict__ b0,
        const float* __restrict__ w1, const float* __restrict__ b1,
        float* __restrict__ pe_out) {
    __shared__ float in_s[8][16];
    __shared__ float h_s[8][128];
    int t = threadIdx.x;
    int base = blockIdx.x * 8;
    if (t < 120) {
        int r = t / 15, c = t % 15;
        int p = base + r;
        float v;
        if (c < 3)      v = attr[p * 3 + c];
        else if (c < 9) v = (p < RIG_) ? (state[p * 6 + (c - 3)] - cent[c - 3]) : 0.0f;
        else            v = state[p * 6 + (c - 9)];
        in_s[r][c] = v;
    }
    __syncthreads();
    float wreg[15];
    #pragma unroll
    for (int k = 0; k < 15; k++) wreg[k] = w0[t * 15 + k];
    float bb = b0[t];
    #pragma unroll
    for (int r = 0; r < 8; r++) {
        float a = bb;
        #pragma unroll
        for (int k = 0; k < 15; k++) a += wreg[k] * in_s[r][k];
        h_s[r][t] = fmaxf(a, 0.f);
    }
    __syncthreads();
    float acc[8];
    float b1v = b1[t];
    #pragma unroll
    for (int r = 0; r < 8; r++) acc[r] = b1v;
    for (int k = 0; k < 128; k += 4) {
        const float4 wv = *(const float4*)(w1 + (size_t)t * 128 + k);
        #pragma unroll
        for (int r = 0; r < 8; r++) {
            const float4 xv = *(const float4*)(&h_s[r][k]);
            acc[r] += wv.x * xv.x + wv.y * xv.y + wv.z * xv.z + wv.w * xv.w;
        }
    }
    #pragma unroll
    for (int r = 0; r < 8; r++) pe_out[(size_t)(base + r) * 128 + t] = fmaxf(acc[r], 0.f);
}

// ---------- 3. relation encoder via MFMA: 32(pad31) -> 128 -> 128 -> 128 ----------
// block = 256 threads = 4 waves; 64 edges per block, 16 per wave
#define IPAD 40
#define HPAD 136
__global__ __launch_bounds__(256) void k_rel_enc_mfma(
        const float* __restrict__ state, const float* __restrict__ attr,
        const float* __restrict__ Ra,
        const int* __restrict__ recv, const int* __restrict__ send,
        const float* __restrict__ cent,
        const unsigned short* __restrict__ w0b,   // [128][32] bf16 (col31=0)
        const float* __restrict__ b0,
        const unsigned short* __restrict__ w1b,   // [128][128]
        const float* __restrict__ b1,
        const unsigned short* __restrict__ w2b,   // [128][128]
        const float* __restrict__ b2,
        unsigned short* __restrict__ re_out) {
    __shared__ unsigned short IN[64 * IPAD];
    __shared__ unsigned short H [64 * HPAD];
    __shared__ unsigned short G [64 * HPAD];
    int t = threadIdx.x;
    long base = (long)blockIdx.x * 64;
    // stage inputs (gather, scalar) as bf16
    for (int it = t; it < 64 * 32; it += 256) {
        int r = it >> 5, c = it & 31;
        long e = base + r;
        float v;
        if (c < 9)       { int p = recv[e]; v = attr2_elem(state, attr, cent, p, c); }
        else if (c < 18) { int p = send[e]; v = attr2_elem(state, attr, cent, p, c - 9); }
        else if (c < 24) { int p = recv[e]; v = state[p * 6 + (c - 18)]; }
        else if (c < 30) { int p = send[e]; v = state[p * 6 + (c - 24)]; }
        else if (c == 30) v = Ra[e];
        else             v = 0.0f;
        IN[r * IPAD + c] = f2b(v);
    }
    __syncthreads();
    int wv = t >> 6, lane = t & 63;
    int m = lane & 15, quad = lane >> 4;
    // ---- layer 1 (K=32) ----
    {
        f32x4 acc[8] = {};
        bf16x8 af = *(const bf16x8*)&IN[(wv * 16 + m) * IPAD + quad * 8];
        #pragma unroll
        for (int nt = 0; nt < 8; nt++) {
            bf16x8 bf = *(const bf16x8*)(w0b + (size_t)(nt * 16 + m) * 32 + quad * 8);
            acc[nt] = __builtin_amdgcn_mfma_f32_16x16x32_bf16(af, bf, acc[nt], 0, 0, 0);
        }
        #pragma unroll
        for (int nt = 0; nt < 8; nt++) {
            int col = nt * 16 + m;
            float bv = b0[col];
            #pragma unroll
            for (int rg = 0; rg < 4; rg++) {
                int row = wv * 16 + quad * 4 + rg;
                H[row * HPAD + col] = f2b(fmaxf(acc[nt][rg] + bv, 0.f));
            }
        }
    }
    __syncthreads();
    // ---- layer 2 (K=128) ----
    {
        f32x4 acc[8] = {};
        for (int kc = 0; kc < 4; kc++) {
            bf16x8 af = *(const bf16x8*)&H[(wv * 16 + m) * HPAD + kc * 32 + quad * 8];
            #pragma unroll
            for (int nt = 0; nt < 8; nt++) {
                bf16x8 bf = *(const bf16x8*)(w1b + (size_t)(nt * 16 + m) * 128 + kc * 32 + quad * 8);
                acc[nt] = __builtin_amdgcn_mfma_f32_16x16x32_bf16(af, bf, acc[nt], 0, 0, 0);
            }
        }
        #pragma unroll
        for (int nt = 0; nt < 8; nt++) {
            int col = nt * 16 + m;
            float bv = b1[col];
            #pragma unroll
            for (int rg = 0; rg < 4; rg++) {
                int row = wv * 16 + quad * 4 + rg;
                G[row * HPAD + col] = f2b(fmaxf(acc[nt][rg] + bv, 0.f));
            }
        }
    }
    __syncthreads();
    // ---- layer 3 (K=128) -> global ----
    {
        f32x4 acc[8] = {};
        for (int kc = 0; kc < 4; kc++) {
            bf16x8 af = *(const bf16x8*)&G[(wv * 16 + m) * HPAD + kc * 32 + quad * 8];
            #pragma unroll
            for (int nt = 0; nt < 8; nt++) {
                bf16x8 bf = *(const bf16x8*)(w2b + (size_t)(nt * 16 + m) * 128 + kc * 32 + quad * 8);
                acc[nt] = __builtin_amdgcn_mfma_f32_16x16x32_bf16(af, bf, acc[nt], 0, 0, 0);
            }
        }
        #pragma unroll
        for (int nt = 0; nt < 8; nt++) {
            int col = nt * 16 + m;
            float bv = b2[col];
            #pragma unroll
            for (int rg = 0; rg < 4; rg++) {
                long row = base + wv * 16 + quad * 4 + rg;
                re_out[row * 128 + col] = f2b(fmaxf(acc[nt][rg] + bv, 0.f));
            }
        }
    }
}

// ---------- 4. propagation edge via MFMA: [re | eff[recv] | eff[send]](384) -> 128, scatter ----------
#define APAD 392
__global__ __launch_bounds__(256) void k_prop_edge_mfma(
        const unsigned short* __restrict__ re,   // [E][128] bf16
        const float* __restrict__ eff,           // [N][128] f32
        const int* __restrict__ recv, const int* __restrict__ send,
        const unsigned short* __restrict__ wb,   // [128][384] bf16
        const float* __restrict__ bias,          // [128]
        float* __restrict__ agg) {
    __shared__ unsigned short A[64 * APAD];
    __shared__ int rv_s[64], sv_s[64];
    int t = threadIdx.x;
    long base = (long)blockIdx.x * 64;
    if (t < 64) { rv_s[t] = recv[base + t]; sv_s[t] = send[base + t]; }
    __syncthreads();
    int r = t >> 2, cq = (t & 3) * 32;
    // re columns [0,128): contiguous bf16 copy
    {
        const unsigned short* src = re + (base + r) * 128 + cq;
        unsigned short* dst = &A[r * APAD + cq];
        #pragma unroll
        for (int i = 0; i < 32; i += 8)
            *(uint4*)(dst + i) = *(const uint4*)(src + i);
    }
    // eff[recv] -> cols [128,256), eff[send] -> cols [256,384): f32 gather + cvt
    #pragma unroll
    for (int half = 0; half < 2; half++) {
        const float* src = eff + (size_t)(half ? sv_s[r] : rv_s[r]) * 128 + cq;
        unsigned short* dst = &A[r * APAD + 128 + half * 128 + cq];
        #pragma unroll
        for (int i = 0; i < 32; i += 8) {
            float4 f0 = *(const float4*)(src + i);
            float4 f1 = *(const float4*)(src + i + 4);
            uint4 v;
            v.x = pk2(f0.x, f0.y); v.y = pk2(f0.z, f0.w);
            v.z = pk2(f1.x, f1.y); v.w = pk2(f1.z, f1.w);
            *(uint4*)(dst + i) = v;
        }
    }
    __syncthreads();
    int wv = t >> 6, lane = t & 63;
    int m = lane & 15, quad = lane >> 4;
    f32x4 acc[8] = {};
    const unsigned short* arow = &A[(wv * 16 + m) * APAD + quad * 8];
    for (int kc = 0; kc < 12; kc++) {
        bf16x8 af = *(const bf16x8*)(arow + kc * 32);
        #pragma unroll
        for (int nt = 0; nt < 8; nt++) {
            bf16x8 bf = *(const bf16x8*)(wb + (size_t)(nt * 16 + m) * 384 + kc * 32 + quad * 8);
            acc[nt] = __builtin_amdgcn_mfma_f32_16x16x32_bf16(af, bf, acc[nt], 0, 0, 0);
        }
    }
    // epilogue: bias + relu + atomic scatter to agg[recv]
    #pragma unroll
    for (int nt = 0; nt < 8; nt++) {
        int col = nt * 16 + m;
        float bv = bias[col];
        #pragma unroll
        for (int rg = 0; rg < 4; rg++) {
            int edge = wv * 16 + quad * 4 + rg;
            float v = fmaxf(acc[nt][rg] + bv, 0.f);
            atomicAdd(&agg[(size_t)rv_s[edge] * 128 + col], v);
        }
    }
}

// ---------- 5. node update: [pe, agg](256) -> 128 (f32) ----------
__global__ __launch_bounds__(128) void k_node(
        const float* __restrict__ pe, const float* __restrict__ agg,
        const float* __restrict__ w, const float* __restrict__ b,
        float* __restrict__ eff) {
    __shared__ float in_s[8][256];
    int t = threadIdx.x;
    long base = (long)blockIdx.x * 8;
    #pragma unroll
    for (int r = 0; r < 8; r++) {
        in_s[r][t]       = pe[(base + r) * 128 + t];
        in_s[r][128 + t] = agg[(base + r) * 128 + t];
    }
    __syncthreads();
    float acc[8];
    float bb = b[t];
    #pragma unroll
    for (int r = 0; r < 8; r++) acc[r] = bb;
    for (int k = 0; k < 256; k += 4) {
        const float4 wv = *(const float4*)(w + (size_t)t * 256 + k);
        #pragma unroll
        for (int r = 0; r < 8; r++) {
            const float4 xv = *(const float4*)(&in_s[r][k]);
            acc[r] += wv.x * xv.x + wv.y * xv.y + wv.z * xv.z + wv.w * xv.w;
        }
    }
    #pragma unroll
    for (int r = 0; r < 8; r++) eff[(base + r) * 128 + t] = fmaxf(acc[r], 0.f);
}

// ---------- 6. pooled mean over effect[:RIG] ----------
__global__ __launch_bounds__(256) void k_pool(const float* __restrict__ eff,
                                              float* __restrict__ pooled) {
    int f = blockIdx.x;
    __shared__ float red[256];
    float s = 0.f;
    for (int r = threadIdx.x; r < RIG_; r += 256) s += eff[(size_t)r * 128 + f];
    red[threadIdx.x] = s; __syncthreads();
    for (int o = 128; o > 0; o >>= 1) {
        if (threadIdx.x < o) red[threadIdx.x] += red[threadIdx.x + o];
        __syncthreads();
    }
    if (threadIdx.x == 0) pooled[f] = red[0] / (float)RIG_;
}

// ---------- 7. rigid head ----------
__global__ __launch_bounds__(128) void k_rigid_head(
        const float* __restrict__ pooled,
        const float* __restrict__ w0, const float* __restrict__ b0,
        const float* __restrict__ w1, const float* __restrict__ b1,
        const float* __restrict__ w2, const float* __restrict__ b2,
        float* __restrict__ rig) {
    __shared__ float pl[128], ha[128], hb[128], tv[7];
    int t = threadIdx.x;
    pl[t] = pooled[t];
    __syncthreads();
    float a = b0[t];
    for (int k = 0; k < 128; k++) a += w0[t * 128 + k] * pl[k];
    ha[t] = fmaxf(a, 0.f);
    __syncthreads();
    a = b1[t];
    for (int k = 0; k < 128; k++) a += w1[t * 128 + k] * ha[k];
    hb[t] = fmaxf(a, 0.f);
    __syncthreads();
    if (t < 7) {
        float s = b2[t];
        for (int k = 0; k < 128; k++) s += w2[t * 128 + k] * hb[k];
        tv[t] = s;
    }
    __syncthreads();
    if (t == 0) {
        float w = tv[0], x = tv[1], y = tv[2], z = tv[3];
        float n = sqrtf(w * w + x * x + y * y + z * z);
        w /= n; x /= n; y /= n; z /= n;
        rig[0] = 1.f - 2.f * (y * y + z * z); rig[1] = 2.f * (x * y + z * w); rig[2] = 2.f * (x * z - y * w);
        rig[3] = 2.f * (x * y - z * w); rig[4] = 1.f - 2.f * (x * x + z * z); rig[5] = 2.f * (y * z + x * w);
        rig[6] = 2.f * (x * z + y * w); rig[7] = 2.f * (y * z - x * w); rig[8] = 1.f - 2.f * (x * x + y * y);
        rig[9] = tv[4]; rig[10] = tv[5]; rig[11] = tv[6];
    }
}

// ---------- 8a. rigid output ----------
__global__ __launch_bounds__(256) void k_rigid_out(
        const float* __restrict__ state, const float* __restrict__ cent,
        const float* __restrict__ rig, float* __restrict__ out) {
    int i = blockIdx.x * 256 + threadIdx.x;
    if (i >= RIG_) return;
    float p0[3], d[3];
    #pragma unroll
    for (int k = 0; k < 3; k++) { p0[k] = state[i * 6 + k]; d[k] = p0[k] - cent[k]; }
    #pragma unroll
    for (int j = 0; j < 3; j++) {
        float p1 = rig[0 * 3 + j] * d[0] + rig[1 * 3 + j] * d[1] + rig[2 * 3 + j] * d[2]
                 + rig[9 + j] + cent[j];
        out[i * 3 + j] = (p1 - p0[j]) * 60.0f;
    }
}

// ---------- 8b. fluid output: 128 -> 128 -> 128 -> 3 (f32) ----------
__global__ __launch_bounds__(128) void k_fluid(
        const float* __restrict__ eff,
        const float* __restrict__ w0, const float* __restrict__ b0,
        const float* __restrict__ w1, const float* __restrict__ b1,
        const float* __restrict__ w2, const float* __restrict__ b2,
        float* __restrict__ out) {
    __shared__ float a_s[8][128], b_s[8][128];
    int t = threadIdx.x;
    long base = RIG_ + (long)blockIdx.x * 8;
    #pragma unroll
    for (int r = 0; r < 8; r++) a_s[r][t] = eff[(base + r) * 128 + t];
    __syncthreads();
    float acc[8];
    float bb = b0[t];
    #pragma unroll
    for (int r = 0; r < 8; r++) acc[r] = bb;
    for (int k = 0; k < 128; k += 4) {
        const float4 wv = *(const float4*)(w0 + (size_t)t * 128 + k);
        #pragma unroll
        for (int r = 0; r < 8; r++) {
            const float4 xv = *(const float4*)(&a_s[r][k]);
            acc[r] += wv.x * xv.x + wv.y * xv.y + wv.z * xv.z + wv.w * xv.w;
        }
    }
    #pragma unroll
    for (int r = 0; r < 8; r++) b_s[r][t] = fmaxf(acc[r], 0.f);
    __syncthreads();
    bb = b1[t];
    #pragma unroll
    for (int r = 0; r < 8; r++) acc[r] = bb;
    for (int k = 0; k < 128; k += 4) {
        const float4 wv = *(const float4*)(w1 + (size_t)t * 128 + k);
        #pragma unroll
        for (int r = 0; r < 8; r++) {
            const float4 xv = *(const float4*)(&b_s[r][k]);
            acc[r] += wv.x * xv.x + wv.y * xv.y + wv.z * xv.z + wv.w * xv.w;
        }
    }
    __syncthreads();
    #pragma unroll
    for (int r = 0; r < 8; r++) a_s[r][t] = fmaxf(acc[r], 0.f);
    __syncthreads();
    if (t < 24) {
        int r = t / 3, o = t % 3;
        float s = b2[o];
        for (int k = 0; k < 128; k++) s += w2[o * 128 + k] * a_s[r][k];
        out[(base + r) * 3 + o] = s;
    }
}

extern "C" void kernel_launch(void* const* d_in, const int* in_sizes, int n_in,
                              void* d_out, int out_size, void* d_ws, size_t ws_size,
                              hipStream_t stream) {
    const float* state = (const float*)d_in[0];
    const float* attr  = (const float*)d_in[1];
    const float* Ra    = (const float*)d_in[2];
    const int*   recv  = (const int*)d_in[3];
    const int*   send  = (const int*)d_in[4];
    const float* pe_w0 = (const float*)d_in[5];  const float* pe_b0 = (const float*)d_in[6];
    const float* pe_w1 = (const float*)d_in[7];  const float* pe_b1 = (const float*)d_in[8];
    const float* re_w0 = (const float*)d_in[9];  const float* re_b0 = (const float*)d_in[10];
    const float* re_w1 = (const float*)d_in[11]; const float* re_b1 = (const float*)d_in[12];
    const float* re_w2 = (const float*)d_in[13]; const float* re_b2 = (const float*)d_in[14];
    const float* rp_w  = (const float*)d_in[15]; const float* rp_b  = (const float*)d_in[16];
    const float* pp_w  = (const float*)d_in[17]; const float* pp_b  = (const float*)d_in[18];
    const float* rg_w0 = (const float*)d_in[19]; const float* rg_b0 = (const float*)d_in[20];
    const float* rg_w1 = (const float*)d_in[21]; const float* rg_b1 = (const float*)d_in[22];
    const float* rg_w2 = (const float*)d_in[23]; const float* rg_b2 = (const float*)d_in[24];
    const float* fl_w0 = (const float*)d_in[25]; const float* fl_b0 = (const float*)d_in[26];
    const float* fl_w1 = (const float*)d_in[27]; const float* fl_b1 = (const float*)d_in[28];
    const float* fl_w2 = (const float*)d_in[29]; const float* fl_b2 = (const float*)d_in[30];
    float* out = (float*)d_out;

    // workspace layout
    float* pe     = (float*)d_ws;                         // N*128 f32
    float* eff    = pe  + (size_t)N_P * 128;              // N*128 f32
    float* agg    = eff + (size_t)N_P * 128;              // N*128 f32
    float* cent   = agg + (size_t)N_P * 128;              // 8
    float* pooled = cent + 8;                             // 128
    float* rig    = pooled + 128;                         // 16 (12 used)
    unsigned short* re    = (unsigned short*)(rig + 16);  // E*128 bf16
    unsigned short* rp_wb = re + (size_t)N_E * 128;       // 128*384
    unsigned short* w0b   = rp_wb + 128 * 384;            // 128*32 (padded)
    unsigned short* w1b   = w0b + 128 * 32;               // 128*128
    unsigned short* w2b   = w1b + 128 * 128;              // 128*128

    size_t need = (size_t)(w2b + 128 * 128 - (unsigned short*)d_ws) * 2;
    if (ws_size < need) {
        fprintf(stderr, "kernel_launch: ws_size %zu < needed %zu\n", ws_size, need);
        return;
    }

    // 0. weight conversion (bf16)
    k_cvt<<<(128 * 384 + 255) / 256, 256, 0, stream>>>(rp_w, rp_wb, 128 * 384);
    k_cvt<<<(128 * 128 + 255) / 256, 256, 0, stream>>>(re_w1, w1b, 128 * 128);
    k_cvt<<<(128 * 128 + 255) / 256, 256, 0, stream>>>(re_w2, w2b, 128 * 128);
    k_cvt_w0pad<<<(128 * 32 + 255) / 256, 256, 0, stream>>>(re_w0, w0b);

    // 1. centroid
    k_centroid<<<6, 256, 0, stream>>>(state, cent);
    // 2. particle encoder
    k_particle_enc<<<N_P / 8, 128, 0, stream>>>(state, attr, cent, pe_w0, pe_b0, pe_w1, pe_b1, pe);
    // 3. relation encoder (MFMA)
    k_rel_enc_mfma<<<N_E / 64, 256, 0, stream>>>(state, attr, Ra, recv, send, cent,
                                                 w0b, re_b0, w1b, re_b1, w2b, re_b2, re);
    // init effect = 0
    hipMemsetAsync(eff, 0, (size_t)N_P * 128 * sizeof(float), stream);
    // 4/5. propagation steps
    for (int step = 0; step < 2; step++) {
        hipMemsetAsync(agg, 0, (size_t)N_P * 128 * sizeof(float), stream);
        k_prop_edge_mfma<<<N_E / 64, 256, 0, stream>>>(re, eff, recv, send, rp_wb, rp_b, agg);
        k_node<<<N_P / 8, 128, 0, stream>>>(pe, agg, pp_w, pp_b, eff);
    }
    // 6. pooled mean
    k_pool<<<128, 256, 0, stream>>>(eff, pooled);
    // 7. rigid head
    k_rigid_head<<<1, 128, 0, stream>>>(pooled, rg_w0, rg_b0, rg_w1, rg_b1, rg_w2, rg_b2, rig);
    // 8a. rigid output
    k_rigid_out<<<(RIG_ + 255) / 256, 256, 0, stream>>>(state, cent, rig, out);
    // 8b. fluid output
    k_fluid<<<(N_P - RIG_) / 8, 128, 0, stream>>>(eff, fl_w0, fl_b0, fl_w1, fl_b1, fl_w2, fl_b2, out);
}

// Round 4
// 1028.452 us; speedup vs baseline: 4.8649x; 1.8878x over previous
//
#include <hip/hip_runtime.h>
#include <hip/hip_bf16.h>
#include <cstdio>

#define N_P   65536
#define N_E   524288
#define RIG_  4096
#define NF_   128

typedef __attribute__((ext_vector_type(8))) short bf16x8;
typedef __attribute__((ext_vector_type(4))) float f32x4;
typedef unsigned short u16;
typedef unsigned int   u32;

__device__ __forceinline__ u16 f2b(float x) {
    __hip_bfloat16 h = __float2bfloat16(x);
    return *(u16*)&h;
}
__device__ __forceinline__ float b2f(u16 u) {
    unsigned v = ((unsigned)u) << 16;
    union { unsigned u; float f; } c; c.u = v; return c.f;
}
__device__ __forceinline__ unsigned pk2(float x, float y) {
    return (unsigned)f2b(x) | ((unsigned)f2b(y) << 16);
}
__device__ __forceinline__ float attr2_elem(const float* __restrict__ state,
                                            const float* __restrict__ attr,
                                            const float* __restrict__ cent,
                                            int p, int j) {
    if (j < 3) return attr[p * 3 + j];
    int k = j - 3;
    return (p < RIG_) ? (state[p * 6 + k] - cent[k]) : 0.0f;
}

// ================= sort: histogram / scan / scatter =================
__global__ __launch_bounds__(256) void k_hist(const int* __restrict__ recv,
                                              u32* __restrict__ cnt) {
    int i = blockIdx.x * 256 + threadIdx.x;
    if (i < N_E) atomicAdd(&cnt[recv[i]], 1u);
}

__global__ __launch_bounds__(256) void k_scan1(u32* __restrict__ data,
                                               u32* __restrict__ bsum) {
    __shared__ u32 s[256];
    int t = threadIdx.x, g = blockIdx.x * 256 + t;
    u32 v = data[g];
    s[t] = v; __syncthreads();
    for (int o = 1; o < 256; o <<= 1) {
        u32 x = (t >= o) ? s[t - o] : 0u;
        __syncthreads();
        s[t] += x;
        __syncthreads();
    }
    data[g] = s[t] - v;              // exclusive within block
    if (t == 255) bsum[blockIdx.x] = s[255];
}

__global__ __launch_bounds__(256) void k_scan2(u32* __restrict__ bsum) {
    __shared__ u32 s[256];
    int t = threadIdx.x;
    u32 v = bsum[t];
    s[t] = v; __syncthreads();
    for (int o = 1; o < 256; o <<= 1) {
        u32 x = (t >= o) ? s[t - o] : 0u;
        __syncthreads();
        s[t] += x;
        __syncthreads();
    }
    bsum[t] = s[t] - v;              // exclusive block offsets
}

__global__ __launch_bounds__(256) void k_scan3(u32* __restrict__ data,
                                               const u32* __restrict__ bsum) {
    int g = blockIdx.x * 256 + threadIdx.x;
    data[g] += bsum[blockIdx.x];
}

__global__ __launch_bounds__(256) void k_scatter(const int* __restrict__ recv,
                                                 const int* __restrict__ send,
                                                 u32* __restrict__ head,
                                                 u32* __restrict__ perm,
                                                 int* __restrict__ srecv,
                                                 int* __restrict__ ssend) {
    int i = blockIdx.x * 256 + threadIdx.x;
    if (i < N_E) {
        int n = recv[i];
        u32 pos = atomicAdd(&head[n], 1u);
        perm[pos] = (u32)i;
        srecv[pos] = n;
        ssend[pos] = send[i];
    }
}

// ================= fused weight conversion =================
struct CvtJob { const float* src; u16* dst; int n; int mode; int bstart; };
struct CvtArgs { CvtJob j[9]; };

__global__ __launch_bounds__(256) void k_cvt_all(CvtArgs a) {
    int b = blockIdx.x;
    int ji = 0;
    #pragma unroll
    for (int k = 1; k < 9; k++) if (b >= a.j[k].bstart) ji = k;
    CvtJob jb = a.j[ji];
    int i = (b - jb.bstart) * 256 + threadIdx.x;
    if (i >= jb.n) return;
    if (jb.mode == 0) {
        jb.dst[i] = f2b(jb.src[i]);
    } else if (jb.mode == 1) {               // [128][31] -> [128][32] pad
        int r = i >> 5, c = i & 31;
        jb.dst[i] = (c < 31) ? f2b(jb.src[r * 31 + c]) : 0;
    } else {                                  // [3][128] -> [16][128] pad
        int r = i >> 7;
        jb.dst[i] = (r < 3) ? f2b(jb.src[i]) : 0;
    }
}

// ================= centroid =================
__global__ __launch_bounds__(256) void k_centroid(const float* __restrict__ state,
                                                  float* __restrict__ cent) {
    int d = blockIdx.x;
    __shared__ float red[256];
    float s = 0.f;
    for (int r = threadIdx.x; r < RIG_; r += 256) s += state[r * 6 + d];
    red[threadIdx.x] = s; __syncthreads();
    for (int o = 128; o > 0; o >>= 1) {
        if (threadIdx.x < o) red[threadIdx.x] += red[threadIdx.x + o];
        __syncthreads();
    }
    if (threadIdx.x == 0) cent[d] = red[0] / (float)RIG_;
}

// ================= particle encoder: 15 -> 128 (scalar) -> 128 (MFMA) =================
#define HPAD 136
__global__ __launch_bounds__(256) void k_particle_enc(
        const float* __restrict__ state, const float* __restrict__ attr,
        const float* __restrict__ cent,
        const float* __restrict__ w0, const float* __restrict__ b0,
        const u16* __restrict__ w1b, const float* __restrict__ b1,
        u16* __restrict__ pe_out) {
    __shared__ float in_s[64][16];
    __shared__ u16 H[64 * HPAD];
    int t = threadIdx.x;
    int base = blockIdx.x * 64;
    for (int it = t; it < 64 * 15; it += 256) {
        int r = it / 15, c = it % 15;
        int p = base + r;
        float v;
        if (c < 3)      v = attr[p * 3 + c];
        else if (c < 9) v = (p < RIG_) ? (state[p * 6 + (c - 3)] - cent[c - 3]) : 0.0f;
        else            v = state[p * 6 + (c - 9)];
        in_s[r][c] = v;
    }
    __syncthreads();
    // layer 1 scalar: 2 row-sets x 128 cols
    {
        int s = t >> 7, col = t & 127;
        float wreg[15];
        #pragma unroll
        for (int k = 0; k < 15; k++) wreg[k] = w0[col * 15 + k];
        float bb = b0[col];
        int r0 = s * 32;
        for (int r = r0; r < r0 + 32; r++) {
            float a = bb;
            #pragma unroll
            for (int k = 0; k < 15; k++) a += wreg[k] * in_s[r][k];
            H[r * HPAD + col] = f2b(fmaxf(a, 0.f));
        }
    }
    __syncthreads();
    // layer 2 MFMA: wave owns 16 rows, 8 col-tiles
    int wv = t >> 6, lane = t & 63;
    int m = lane & 15, quad = lane >> 4;
    f32x4 acc[8] = {};
    for (int kc = 0; kc < 4; kc++) {
        bf16x8 af = *(const bf16x8*)&H[(wv * 16 + m) * HPAD + kc * 32 + quad * 8];
        #pragma unroll
        for (int nt = 0; nt < 8; nt++) {
            bf16x8 bf = *(const bf16x8*)(w1b + (size_t)(nt * 16 + m) * 128 + kc * 32 + quad * 8);
            acc[nt] = __builtin_amdgcn_mfma_f32_16x16x32_bf16(af, bf, acc[nt], 0, 0, 0);
        }
    }
    #pragma unroll
    for (int nt = 0; nt < 8; nt++) {
        int col = nt * 16 + m;
        float bv = b1[col];
        #pragma unroll
        for (int rg = 0; rg < 4; rg++) {
            int row = wv * 16 + quad * 4 + rg;
            pe_out[(size_t)(base + row) * 128 + col] = f2b(fmaxf(acc[nt][rg] + bv, 0.f));
        }
    }
}

// ================= relation encoder (sorted output): 32 -> 128 -> 128 -> 128 =================
#define IPAD 40
__global__ __launch_bounds__(256) void k_rel_enc(
        const float* __restrict__ state, const float* __restrict__ attr,
        const float* __restrict__ Ra,
        const u32* __restrict__ perm,
        const int* __restrict__ srecv, const int* __restrict__ ssend,
        const float* __restrict__ cent,
        const u16* __restrict__ w0b, const float* __restrict__ b0,
        const u16* __restrict__ w1b, const float* __restrict__ b1,
        const u16* __restrict__ w2b, const float* __restrict__ b2,
        u16* __restrict__ re_out) {
    __shared__ u16 IN[64 * IPAD];
    __shared__ u16 H[64 * HPAD];
    __shared__ u16 G[64 * HPAD];
    int t = threadIdx.x;
    long base = (long)blockIdx.x * 64;
    for (int it = t; it < 64 * 32; it += 256) {
        int r = it >> 5, c = it & 31;
        long i = base + r;
        float v;
        if (c < 9)       { int p = srecv[i]; v = attr2_elem(state, attr, cent, p, c); }
        else if (c < 18) { int p = ssend[i]; v = attr2_elem(state, attr, cent, p, c - 9); }
        else if (c < 24) { int p = srecv[i]; v = state[p * 6 + (c - 18)]; }
        else if (c < 30) { int p = ssend[i]; v = state[p * 6 + (c - 24)]; }
        else if (c == 30) v = Ra[perm[i]];
        else              v = 0.0f;
        IN[r * IPAD + c] = f2b(v);
    }
    __syncthreads();
    int wv = t >> 6, lane = t & 63;
    int m = lane & 15, quad = lane >> 4;
    // layer 1 (K=32)
    {
        f32x4 acc[8] = {};
        bf16x8 af = *(const bf16x8*)&IN[(wv * 16 + m) * IPAD + quad * 8];
        #pragma unroll
        for (int nt = 0; nt < 8; nt++) {
            bf16x8 bf = *(const bf16x8*)(w0b + (size_t)(nt * 16 + m) * 32 + quad * 8);
            acc[nt] = __builtin_amdgcn_mfma_f32_16x16x32_bf16(af, bf, acc[nt], 0, 0, 0);
        }
        #pragma unroll
        for (int nt = 0; nt < 8; nt++) {
            int col = nt * 16 + m;
            float bv = b0[col];
            #pragma unroll
            for (int rg = 0; rg < 4; rg++) {
                int row = wv * 16 + quad * 4 + rg;
                H[row * HPAD + col] = f2b(fmaxf(acc[nt][rg] + bv, 0.f));
            }
        }
    }
    __syncthreads();
    // layer 2
    {
        f32x4 acc[8] = {};
        for (int kc = 0; kc < 4; kc++) {
            bf16x8 af = *(const bf16x8*)&H[(wv * 16 + m) * HPAD + kc * 32 + quad * 8];
            #pragma unroll
            for (int nt = 0; nt < 8; nt++) {
                bf16x8 bf = *(const bf16x8*)(w1b + (size_t)(nt * 16 + m) * 128 + kc * 32 + quad * 8);
                acc[nt] = __builtin_amdgcn_mfma_f32_16x16x32_bf16(af, bf, acc[nt], 0, 0, 0);
            }
        }
        #pragma unroll
        for (int nt = 0; nt < 8; nt++) {
            int col = nt * 16 + m;
            float bv = b1[col];
            #pragma unroll
            for (int rg = 0; rg < 4; rg++) {
                int row = wv * 16 + quad * 4 + rg;
                G[row * HPAD + col] = f2b(fmaxf(acc[nt][rg] + bv, 0.f));
            }
        }
    }
    __syncthreads();
    // layer 3 -> global (sorted order)
    {
        f32x4 acc[8] = {};
        for (int kc = 0; kc < 4; kc++) {
            bf16x8 af = *(const bf16x8*)&G[(wv * 16 + m) * HPAD + kc * 32 + quad * 8];
            #pragma unroll
            for (int nt = 0; nt < 8; nt++) {
                bf16x8 bf = *(const bf16x8*)(w2b + (size_t)(nt * 16 + m) * 128 + kc * 32 + quad * 8);
                acc[nt] = __builtin_amdgcn_mfma_f32_16x16x32_bf16(af, bf, acc[nt], 0, 0, 0);
            }
        }
        #pragma unroll
        for (int nt = 0; nt < 8; nt++) {
            int col = nt * 16 + m;
            float bv = b2[col];
            #pragma unroll
            for (int rg = 0; rg < 4; rg++) {
                long row = base + wv * 16 + quad * 4 + rg;
                re_out[row * 128 + col] = f2b(fmaxf(acc[nt][rg] + bv, 0.f));
            }
        }
    }
}

// ================= propagation edge (sorted, run-length epilogue) =================
#define APAD 392
__global__ __launch_bounds__(256) void k_prop(
        const u16* __restrict__ re_s,    // [E][128] bf16, sorted by recv
        const u16* __restrict__ effb,    // [N][128] bf16
        const int* __restrict__ srecv, const int* __restrict__ ssend,
        const u16* __restrict__ wb,      // [128][384] bf16
        const float* __restrict__ bias,
        float* __restrict__ agg,
        int nkc) {                        // 4 (step1, eff=0) or 12
    __shared__ __align__(16) u16 A[64 * APAD];   // 50176 B, overlaid by S (f32) in epilogue
    __shared__ int rv[64], sv[64];
    int t = threadIdx.x;
    long base = (long)blockIdx.x * 64;
    if (t < 64) { rv[t] = srecv[base + t]; sv[t] = ssend[base + t]; }
    __syncthreads();
    int r = t >> 2, q = t & 3;
    // stage re_s (contiguous)
    {
        const u16* src = re_s + (base + r) * 128 + q * 32;
        u16* dst = &A[r * APAD + q * 32];
        #pragma unroll
        for (int i = 0; i < 32; i += 8)
            *(uint4*)(dst + i) = *(const uint4*)(src + i);
    }
    if (nkc > 4) {
        #pragma unroll
        for (int half = 0; half < 2; half++) {
            const u16* src = effb + (size_t)(half ? sv[r] : rv[r]) * 128 + q * 32;
            u16* dst = &A[r * APAD + 128 + half * 128 + q * 32];
            #pragma unroll
            for (int i = 0; i < 32; i += 8)
                *(uint4*)(dst + i) = *(const uint4*)(src + i);
        }
    }
    __syncthreads();
    // MFMA: wave = (col-half ch, row-half rh); 4 col-tiles x 2 row-tiles each
    int wv = t >> 6, lane = t & 63;
    int ch = wv & 1, rh = wv >> 1;
    int m = lane & 15, quad = lane >> 4;
    f32x4 acc[2][4] = {};
    for (int kc = 0; kc < nkc; kc++) {
        bf16x8 bfr[4];
        #pragma unroll
        for (int j = 0; j < 4; j++)
            bfr[j] = *(const bf16x8*)(wb + (size_t)((ch * 4 + j) * 16 + m) * 384 + kc * 32 + quad * 8);
        #pragma unroll
        for (int rt = 0; rt < 2; rt++) {
            bf16x8 af = *(const bf16x8*)&A[(rh * 32 + rt * 16 + m) * APAD + kc * 32 + quad * 8];
            #pragma unroll
            for (int j = 0; j < 4; j++)
                acc[rt][j] = __builtin_amdgcn_mfma_f32_16x16x32_bf16(af, bfr[j], acc[rt][j], 0, 0, 0);
        }
    }
    __syncthreads();           // all A reads done; reuse as f32 S[64][132]
    float* S = (float*)A;
    #pragma unroll
    for (int rt = 0; rt < 2; rt++)
        #pragma unroll
        for (int j = 0; j < 4; j++) {
            int col = (ch * 4 + j) * 16 + m;
            float bv = bias[col];
            #pragma unroll
            for (int rg = 0; rg < 4; rg++) {
                int row = rh * 32 + rt * 16 + quad * 4 + rg;
                S[row * 132 + col] = fmaxf(acc[rt][j][rg] + bv, 0.f);
            }
        }
    __syncthreads();
    // run-length segmented reduce over sorted recv (uniform branches per row-set)
    {
        int s = t >> 7, col = t & 127;
        int r0 = s * 32;
        int cur = rv[r0];
        float a = S[r0 * 132 + col];
        for (int rr = r0 + 1; rr < r0 + 32; rr++) {
            int n = rv[rr];
            float v = S[rr * 132 + col];
            if (n == cur) a += v;
            else {
                atomicAdd(&agg[(size_t)cur * 128 + col], a);
                cur = n; a = v;
            }
        }
        atomicAdd(&agg[(size_t)cur * 128 + col], a);
    }
}

// ================= node update MFMA: [pe_b | agg](256) -> 128 =================
#define NPAD 264
__global__ __launch_bounds__(256) void k_node(
        const u16* __restrict__ pe_b, const float* __restrict__ agg,
        const u16* __restrict__ wb,   // [128][256] bf16
        const float* __restrict__ bias,
        u16* __restrict__ effb) {
    __shared__ __align__(16) u16 A[64 * NPAD];   // 33792 B
    int t = threadIdx.x;
    long base = (long)blockIdx.x * 64;
    int r = t >> 2, q = t & 3;
    {
        const u16* src = pe_b + (base + r) * 128 + q * 32;
        u16* dst = &A[r * NPAD + q * 32];
        #pragma unroll
        for (int i = 0; i < 32; i += 8)
            *(uint4*)(dst + i) = *(const uint4*)(src + i);
    }
    {
        const float* src = agg + (base + r) * 128 + q * 32;
        u16* dst = &A[r * NPAD + 128 + q * 32];
        #pragma unroll
        for (int i = 0; i < 32; i += 8) {
            float4 f0 = *(const float4*)(src + i);
            float4 f1 = *(const float4*)(src + i + 4);
            uint4 v;
            v.x = pk2(f0.x, f0.y); v.y = pk2(f0.z, f0.w);
            v.z = pk2(f1.x, f1.y); v.w = pk2(f1.z, f1.w);
            *(uint4*)(dst + i) = v;
        }
    }
    __syncthreads();
    int wv = t >> 6, lane = t & 63;
    int ch = wv & 1, rh = wv >> 1;
    int m = lane & 15, quad = lane >> 4;
    f32x4 acc[2][4] = {};
    for (int kc = 0; kc < 8; kc++) {
        bf16x8 bfr[4];
        #pragma unroll
        for (int j = 0; j < 4; j++)
            bfr[j] = *(const bf16x8*)(wb + (size_t)((ch * 4 + j) * 16 + m) * 256 + kc * 32 + quad * 8);
        #pragma unroll
        for (int rt = 0; rt < 2; rt++) {
            bf16x8 af = *(const bf16x8*)&A[(rh * 32 + rt * 16 + m) * NPAD + kc * 32 + quad * 8];
            #pragma unroll
            for (int j = 0; j < 4; j++)
                acc[rt][j] = __builtin_amdgcn_mfma_f32_16x16x32_bf16(af, bfr[j], acc[rt][j], 0, 0, 0);
        }
    }
    #pragma unroll
    for (int rt = 0; rt < 2; rt++)
        #pragma unroll
        for (int j = 0; j < 4; j++) {
            int col = (ch * 4 + j) * 16 + m;
            float bv = bias[col];
            #pragma unroll
            for (int rg = 0; rg < 4; rg++) {
                int row = rh * 32 + rt * 16 + quad * 4 + rg;
                effb[(base + row) * 128 + col] = f2b(fmaxf(acc[rt][j][rg] + bv, 0.f));
            }
        }
}

// ================= pooled mean over effect[:RIG] (bf16 in) =================
__global__ __launch_bounds__(256) void k_pool(const u16* __restrict__ effb,
                                              float* __restrict__ pooled) {
    int f = blockIdx.x;
    __shared__ float red[256];
    float s = 0.f;
    for (int r = threadIdx.x; r < RIG_; r += 256) s += b2f(effb[(size_t)r * 128 + f]);
    red[threadIdx.x] = s; __syncthreads();
    for (int o = 128; o > 0; o >>= 1) {
        if (threadIdx.x < o) red[threadIdx.x] += red[threadIdx.x + o];
        __syncthreads();
    }
    if (threadIdx.x == 0) pooled[f] = red[0] / (float)RIG_;
}

// ================= rigid head =================
__global__ __launch_bounds__(128) void k_rigid_head(
        const float* __restrict__ pooled,
        const float* __restrict__ w0, const float* __restrict__ b0,
        const float* __restrict__ w1, const float* __restrict__ b1,
        const float* __restrict__ w2, const float* __restrict__ b2,
        float* __restrict__ rig) {
    __shared__ float pl[128], ha[128], hb[128], tv[7];
    int t = threadIdx.x;
    pl[t] = pooled[t];
    __syncthreads();
    float a = b0[t];
    for (int k = 0; k < 128; k++) a += w0[t * 128 + k] * pl[k];
    ha[t] = fmaxf(a, 0.f);
    __syncthreads();
    a = b1[t];
    for (int k = 0; k < 128; k++) a += w1[t * 128 + k] * ha[k];
    hb[t] = fmaxf(a, 0.f);
    __syncthreads();
    if (t < 7) {
        float s = b2[t];
        for (int k = 0; k < 128; k++) s += w2[t * 128 + k] * hb[k];
        tv[t] = s;
    }
    __syncthreads();
    if (t == 0) {
        float w = tv[0], x = tv[1], y = tv[2], z = tv[3];
        float n = sqrtf(w * w + x * x + y * y + z * z);
        w /= n; x /= n; y /= n; z /= n;
        rig[0] = 1.f - 2.f * (y * y + z * z); rig[1] = 2.f * (x * y + z * w); rig[2] = 2.f * (x * z - y * w);
        rig[3] = 2.f * (x * y - z * w); rig[4] = 1.f - 2.f * (x * x + z * z); rig[5] = 2.f * (y * z + x * w);
        rig[6] = 2.f * (x * z + y * w); rig[7] = 2.f * (y * z - x * w); rig[8] = 1.f - 2.f * (x * x + y * y);
        rig[9] = tv[4]; rig[10] = tv[5]; rig[11] = tv[6];
    }
}

// ================= rigid output =================
__global__ __launch_bounds__(256) void k_rigid_out(
        const float* __restrict__ state, const float* __restrict__ cent,
        const float* __restrict__ rig, float* __restrict__ out) {
    int i = blockIdx.x * 256 + threadIdx.x;
    if (i >= RIG_) return;
    float p0[3], d[3];
    #pragma unroll
    for (int k = 0; k < 3; k++) { p0[k] = state[i * 6 + k]; d[k] = p0[k] - cent[k]; }
    #pragma unroll
    for (int j = 0; j < 3; j++) {
        float p1 = rig[0 * 3 + j] * d[0] + rig[1 * 3 + j] * d[1] + rig[2 * 3 + j] * d[2]
                 + rig[9 + j] + cent[j];
        out[i * 3 + j] = (p1 - p0[j]) * 60.0f;
    }
}

// ================= fluid MFMA: 128 -> 128 -> 128 -> 3(pad16) =================
__global__ __launch_bounds__(256) void k_fluid(
        const u16* __restrict__ effb,
        const u16* __restrict__ w0b, const float* __restrict__ b0,
        const u16* __restrict__ w1b, const float* __restrict__ b1,
        const u16* __restrict__ w2b, const float* __restrict__ b2,
        float* __restrict__ out) {
    __shared__ u16 H0[64 * HPAD];
    __shared__ u16 H1[64 * HPAD];
    int t = threadIdx.x;
    long base = RIG_ + (long)blockIdx.x * 64;
    int r = t >> 2, q = t & 3;
    {
        const u16* src = effb + (base + r) * 128 + q * 32;
        u16* dst = &H0[r * HPAD + q * 32];
        #pragma unroll
        for (int i = 0; i < 32; i += 8)
            *(uint4*)(dst + i) = *(const uint4*)(src + i);
    }
    __syncthreads();
    int wv = t >> 6, lane = t & 63;
    int m = lane & 15, quad = lane >> 4;
    // layer 1
    {
        f32x4 acc[8] = {};
        for (int kc = 0; kc < 4; kc++) {
            bf16x8 af = *(const bf16x8*)&H0[(wv * 16 + m) * HPAD + kc * 32 + quad * 8];
            #pragma unroll
            for (int nt = 0; nt < 8; nt++) {
                bf16x8 bf = *(const bf16x8*)(w0b + (size_t)(nt * 16 + m) * 128 + kc * 32 + quad * 8);
                acc[nt] = __builtin_amdgcn_mfma_f32_16x16x32_bf16(af, bf, acc[nt], 0, 0, 0);
            }
        }
        #pragma unroll
        for (int nt = 0; nt < 8; nt++) {
            int col = nt * 16 + m;
            float bv = b0[col];
            #pragma unroll
            for (int rg = 0; rg < 4; rg++) {
                int row = wv * 16 + quad * 4 + rg;
                H1[row * HPAD + col] = f2b(fmaxf(acc[nt][rg] + bv, 0.f));
            }
        }
    }
    __syncthreads();
    // layer 2 (write back into H0)
    {
        f32x4 acc[8] = {};
        for (int kc = 0; kc < 4; kc++) {
            bf16x8 af = *(const bf16x8*)&H1[(wv * 16 + m) * HPAD + kc * 32 + quad * 8];
            #pragma unroll
            for (int nt = 0; nt < 8; nt++) {
                bf16x8 bf = *(const bf16x8*)(w1b + (size_t)(nt * 16 + m) * 128 + kc * 32 + quad * 8);
                acc[nt] = __builtin_amdgcn_mfma_f32_16x16x32_bf16(af, bf, acc[nt], 0, 0, 0);
            }
        }
        __syncthreads();
        #pragma unroll
        for (int nt = 0; nt < 8; nt++) {
            int col = nt * 16 + m;
            float bv = b1[col];
            #pragma unroll
            for (int rg = 0; rg < 4; rg++) {
                int row = wv * 16 + quad * 4 + rg;
                H0[row * HPAD + col] = f2b(fmaxf(acc[nt][rg] + bv, 0.f));
            }
        }
    }
    __syncthreads();
    // layer 3: 16 output cols (3 used)
    {
        f32x4 acc = {};
        for (int kc = 0; kc < 4; kc++) {
            bf16x8 af = *(const bf16x8*)&H0[(wv * 16 + m) * HPAD + kc * 32 + quad * 8];
            bf16x8 bf = *(const bf16x8*)(w2b + (size_t)m * 128 + kc * 32 + quad * 8);
            acc = __builtin_amdgcn_mfma_f32_16x16x32_bf16(af, bf, acc, 0, 0, 0);
        }
        if (m < 3) {
            float bv = b2[m];
            #pragma unroll
            for (int rg = 0; rg < 4; rg++) {
                long row = base + wv * 16 + quad * 4 + rg;
                out[row * 3 + m] = acc[rg] + bv;
            }
        }
    }
}

// ================= host =================
extern "C" void kernel_launch(void* const* d_in, const int* in_sizes, int n_in,
                              void* d_out, int out_size, void* d_ws, size_t ws_size,
                              hipStream_t stream) {
    const float* state = (const float*)d_in[0];
    const float* attr  = (const float*)d_in[1];
    const float* Ra    = (const float*)d_in[2];
    const int*   recv  = (const int*)d_in[3];
    const int*   send  = (const int*)d_in[4];
    const float* pe_w0 = (const float*)d_in[5];  const float* pe_b0 = (const float*)d_in[6];
    const float* pe_w1 = (const float*)d_in[7];  const float* pe_b1 = (const float*)d_in[8];
    const float* re_w0 = (const float*)d_in[9];  const float* re_b0 = (const float*)d_in[10];
    const float* re_w1 = (const float*)d_in[11]; const float* re_b1 = (const float*)d_in[12];
    const float* re_w2 = (const float*)d_in[13]; const float* re_b2 = (const float*)d_in[14];
    const float* rp_w  = (const float*)d_in[15]; const float* rp_b  = (const float*)d_in[16];
    const float* pp_w  = (const float*)d_in[17]; const float* pp_b  = (const float*)d_in[18];
    const float* rg_w0 = (const float*)d_in[19]; const float* rg_b0 = (const float*)d_in[20];
    const float* rg_w1 = (const float*)d_in[21]; const float* rg_b1 = (const float*)d_in[22];
    const float* rg_w2 = (const float*)d_in[23]; const float* rg_b2 = (const float*)d_in[24];
    const float* fl_w0 = (const float*)d_in[25]; const float* fl_b0 = (const float*)d_in[26];
    const float* fl_w1 = (const float*)d_in[27]; const float* fl_b1 = (const float*)d_in[28];
    const float* fl_w2 = (const float*)d_in[29]; const float* fl_b2 = (const float*)d_in[30];
    float* out = (float*)d_out;

    // ---- workspace carve-out ----
    char* p = (char*)d_ws;
    auto alloc = [&](size_t bytes) { char* r = p; p += (bytes + 255) / 256 * 256; return r; };
    float* cent    = (float*)alloc(8 * 4);
    float* pooled  = (float*)alloc(128 * 4);
    float* rig     = (float*)alloc(16 * 4);
    u32*   rowhead = (u32*)alloc((size_t)N_P * 4);
    u32*   bsum    = (u32*)alloc(256 * 4);
    u32*   perm    = (u32*)alloc((size_t)N_E * 4);
    int*   srecv   = (int*)alloc((size_t)N_E * 4);
    int*   ssend   = (int*)alloc((size_t)N_E * 4);
    float* agg     = (float*)alloc((size_t)N_P * 128 * 4);
    u16*   re_s    = (u16*)alloc((size_t)N_E * 128 * 2);
    u16*   pe_b    = (u16*)alloc((size_t)N_P * 128 * 2);
    u16*   effb    = (u16*)alloc((size_t)N_P * 128 * 2);
    u16*   rpwb    = (u16*)alloc(128 * 384 * 2);
    u16*   rw0b    = (u16*)alloc(128 * 32 * 2);
    u16*   rw1b    = (u16*)alloc(128 * 128 * 2);
    u16*   rw2b    = (u16*)alloc(128 * 128 * 2);
    u16*   ppwb    = (u16*)alloc(128 * 256 * 2);
    u16*   pew1b   = (u16*)alloc(128 * 128 * 2);
    u16*   flw0b   = (u16*)alloc(128 * 128 * 2);
    u16*   flw1b   = (u16*)alloc(128 * 128 * 2);
    u16*   flw2b   = (u16*)alloc(16 * 128 * 2);
    size_t need = (size_t)(p - (char*)d_ws);
    if (ws_size < need) {
        fprintf(stderr, "kernel_launch: ws_size %zu < needed %zu\n", ws_size, need);
        return;
    }

    // ---- sort edges by recv (counting sort) ----
    hipMemsetAsync(rowhead, 0, (size_t)N_P * 4, stream);
    k_hist<<<N_E / 256, 256, 0, stream>>>(recv, rowhead);
    k_scan1<<<N_P / 256, 256, 0, stream>>>(rowhead, bsum);
    k_scan2<<<1, 256, 0, stream>>>(bsum);
    k_scan3<<<N_P / 256, 256, 0, stream>>>(rowhead, bsum);
    k_scatter<<<N_E / 256, 256, 0, stream>>>(recv, send, rowhead, perm, srecv, ssend);

    // ---- weight conversion (single fused launch) ----
    CvtArgs ca;
    int bs = 0;
    auto addjob = [&](int idx, const float* s, u16* d, int n, int mode) {
        ca.j[idx] = {s, d, n, mode, bs};
        bs += (n + 255) / 256;
    };
    addjob(0, rp_w,  rpwb,  128 * 384, 0);
    addjob(1, re_w1, rw1b,  128 * 128, 0);
    addjob(2, re_w2, rw2b,  128 * 128, 0);
    addjob(3, pp_w,  ppwb,  128 * 256, 0);
    addjob(4, pe_w1, pew1b, 128 * 128, 0);
    addjob(5, fl_w0, flw0b, 128 * 128, 0);
    addjob(6, fl_w1, flw1b, 128 * 128, 0);
    addjob(7, re_w0, rw0b,  128 * 32,  1);
    addjob(8, fl_w2, flw2b, 16 * 128,  2);
    k_cvt_all<<<bs, 256, 0, stream>>>(ca);

    // ---- encoders ----
    k_centroid<<<6, 256, 0, stream>>>(state, cent);
    k_particle_enc<<<N_P / 64, 256, 0, stream>>>(state, attr, cent,
                                                 pe_w0, pe_b0, pew1b, pe_b1, pe_b);
    k_rel_enc<<<N_E / 64, 256, 0, stream>>>(state, attr, Ra, perm, srecv, ssend, cent,
                                            rw0b, re_b0, rw1b, re_b1, rw2b, re_b2, re_s);

    // ---- propagation ----
    for (int step = 0; step < 2; step++) {
        hipMemsetAsync(agg, 0, (size_t)N_P * 128 * 4, stream);
        k_prop<<<N_E / 64, 256, 0, stream>>>(re_s, effb, srecv, ssend, rpwb, rp_b, agg,
                                             step == 0 ? 4 : 12);
        k_node<<<N_P / 64, 256, 0, stream>>>(pe_b, agg, ppwb, pp_b, effb);
    }

    // ---- heads ----
    k_pool<<<128, 256, 0, stream>>>(effb, pooled);
    k_rigid_head<<<1, 128, 0, stream>>>(pooled, rg_w0, rg_b0, rg_w1, rg_b1, rg_w2, rg_b2, rig);
    k_rigid_out<<<(RIG_ + 255) / 256, 256, 0, stream>>>(state, cent, rig, out);
    k_fluid<<<(N_P - RIG_) / 64, 256, 0, stream>>>(effb, flw0b, fl_b0, flw1b, fl_b1,
                                                   flw2b, fl_b2, out);
}

// Round 5
// 848.826 us; speedup vs baseline: 5.8944x; 1.2116x over previous
//
#include <hip/hip_runtime.h>
#include <hip/hip_bf16.h>
#include <cstdio>

#define N_P   65536
#define N_E   524288
#define RIG_  4096

typedef __attribute__((ext_vector_type(8))) short bf16x8;
typedef __attribute__((ext_vector_type(4))) float f32x4;
typedef unsigned short u16;
typedef unsigned int   u32;

__device__ __forceinline__ u16 f2b(float x) {
    __hip_bfloat16 h = __float2bfloat16(x);
    return *(u16*)&h;
}
__device__ __forceinline__ float b2f(u16 u) {
    union { unsigned u; float f; } c; c.u = ((unsigned)u) << 16; return c.f;
}
__device__ __forceinline__ unsigned pk2(float x, float y) {
    return (unsigned)f2b(x) | ((unsigned)f2b(y) << 16);
}
#define MFMA(a,b,c) __builtin_amdgcn_mfma_f32_16x16x32_bf16((a),(b),(c),0,0,0)

// ================= sort: histogram / scan / scatter =================
__global__ __launch_bounds__(256) void k_hist(const int* __restrict__ recv,
                                              u32* __restrict__ cnt) {
    int i = blockIdx.x * 256 + threadIdx.x;
    if (i < N_E) atomicAdd(&cnt[recv[i]], 1u);
}
__global__ __launch_bounds__(256) void k_scan1(u32* __restrict__ data,
                                               u32* __restrict__ bsum) {
    __shared__ u32 s[256];
    int t = threadIdx.x, g = blockIdx.x * 256 + t;
    u32 v = data[g];
    s[t] = v; __syncthreads();
    for (int o = 1; o < 256; o <<= 1) {
        u32 x = (t >= o) ? s[t - o] : 0u;
        __syncthreads(); s[t] += x; __syncthreads();
    }
    data[g] = s[t] - v;
    if (t == 255) bsum[blockIdx.x] = s[255];
}
__global__ __launch_bounds__(256) void k_scan2(u32* __restrict__ bsum) {
    __shared__ u32 s[256];
    int t = threadIdx.x;
    u32 v = bsum[t];
    s[t] = v; __syncthreads();
    for (int o = 1; o < 256; o <<= 1) {
        u32 x = (t >= o) ? s[t - o] : 0u;
        __syncthreads(); s[t] += x; __syncthreads();
    }
    bsum[t] = s[t] - v;
}
__global__ __launch_bounds__(256) void k_scan3(u32* __restrict__ data,
                                               const u32* __restrict__ bsum) {
    int g = blockIdx.x * 256 + threadIdx.x;
    data[g] += bsum[blockIdx.x];
}
__global__ __launch_bounds__(256) void k_scatter(const int* __restrict__ recv,
                                                 const int* __restrict__ send,
                                                 u32* __restrict__ head,
                                                 u32* __restrict__ perm,
                                                 int* __restrict__ srecv,
                                                 int* __restrict__ ssend) {
    int i = blockIdx.x * 256 + threadIdx.x;
    if (i < N_E) {
        int n = recv[i];
        u32 pos = atomicAdd(&head[n], 1u);
        perm[pos] = (u32)i;
        srecv[pos] = n;
        ssend[pos] = send[i];
    }
}

// ================= fused weight conversion =================
// modes: 0 plain; 2 pad-rows [3][128]->[16][128]; 3 col-slice stride 384;
// 4 col-slice stride 256; 5 W0r-select; 6 W0s-select; 7 pad15->32
struct CvtJob { const float* src; u16* dst; int n; int mode; int bstart; };
struct CvtArgs { CvtJob j[14]; };

__global__ __launch_bounds__(256) void k_cvt_all(CvtArgs a) {
    int b = blockIdx.x;
    int ji = 0;
    #pragma unroll
    for (int k = 1; k < 14; k++) if (b >= a.j[k].bstart) ji = k;
    CvtJob jb = a.j[ji];
    int i = (b - jb.bstart) * 256 + threadIdx.x;
    if (i >= jb.n) return;
    if (jb.mode == 0) {
        jb.dst[i] = f2b(jb.src[i]);
    } else if (jb.mode == 2) {
        int r = i >> 7;
        jb.dst[i] = (r < 3) ? f2b(jb.src[i]) : 0;
    } else if (jb.mode == 3) {
        int r = i >> 7, c = i & 127;
        jb.dst[i] = f2b(jb.src[r * 384 + c]);
    } else if (jb.mode == 4) {
        int r = i >> 7, c = i & 127;
        jb.dst[i] = f2b(jb.src[r * 256 + c]);
    } else if (jb.mode == 5) {               // W0r: [attr2_r(9), state_r(6)] cols
        int r = i >> 5, c = i & 31;
        float v = 0.f;
        if (c < 9)       v = jb.src[r * 31 + c];
        else if (c < 15) v = jb.src[r * 31 + 18 + (c - 9)];
        jb.dst[i] = f2b(v);
    } else if (jb.mode == 6) {               // W0s: [attr2_s(9), state_s(6)] cols
        int r = i >> 5, c = i & 31;
        float v = 0.f;
        if (c < 9)       v = jb.src[r * 31 + 9 + c];
        else if (c < 15) v = jb.src[r * 31 + 24 + (c - 9)];
        jb.dst[i] = f2b(v);
    } else {                                  // mode 7: [128][15] -> [128][32]
        int r = i >> 5, c = i & 31;
        jb.dst[i] = (c < 15) ? f2b(jb.src[r * 15 + c]) : 0;
    }
}

// ================= centroid =================
__global__ __launch_bounds__(256) void k_centroid(const float* __restrict__ state,
                                                  float* __restrict__ cent) {
    int d = blockIdx.x;
    __shared__ float red[256];
    float s = 0.f;
    for (int r = threadIdx.x; r < RIG_; r += 256) s += state[r * 6 + d];
    red[threadIdx.x] = s; __syncthreads();
    for (int o = 128; o > 0; o >>= 1) {
        if (threadIdx.x < o) red[threadIdx.x] += red[threadIdx.x + o];
        __syncthreads();
    }
    if (threadIdx.x == 0) cent[d] = red[0] / (float)RIG_;
}

// ================= particle: feat(15) -> {P, Q, pe MLP, T} =================
__global__ __launch_bounds__(256) void k_particle_ext(
        const float* __restrict__ state, const float* __restrict__ attr,
        const float* __restrict__ cent,
        const u16* __restrict__ w0r, const u16* __restrict__ w0s,   // [128][32]
        const u16* __restrict__ pew0, const float* __restrict__ pe_b0, // [128][32]
        const u16* __restrict__ pew1, const float* __restrict__ pe_b1, // [128][128]
        const u16* __restrict__ wp,                                    // [128][128]
        u16* __restrict__ P, u16* __restrict__ Q, u16* __restrict__ T) {
    __shared__ float in_s[64][16];
    __shared__ u16 INF[64 * 32];
    __shared__ u16 BUFB[64 * 128];
    __shared__ u16 BUFA[64 * 128];
    __shared__ float b0_s[128], b1_s[128];
    int t = threadIdx.x;
    int base = blockIdx.x * 64;
    if (t < 128) { b0_s[t] = pe_b0[t]; b1_s[t] = pe_b1[t]; }
    for (int it = t; it < 64 * 15; it += 256) {
        int r = it / 15, c = it % 15;
        int p = base + r;
        float v;
        if (c < 3)      v = attr[p * 3 + c];
        else if (c < 9) v = (p < RIG_) ? (state[p * 6 + (c - 3)] - cent[c - 3]) : 0.0f;
        else            v = state[p * 6 + (c - 9)];
        in_s[r][c] = v;
    }
    __syncthreads();
    int wv = t >> 6, kq4 = (t >> 4) & 3, m = t & 15;
    {
        int e = wv * 16 + m;
        u16 tmp[8];
        #pragma unroll
        for (int j = 0; j < 8; j++) {
            int k = kq4 * 8 + j;
            tmp[j] = (k < 15) ? f2b(in_s[e][k]) : (u16)0;
        }
        *(uint4*)&INF[((wv * 4 + kq4) * 16 + m) * 8] = *(uint4*)tmp;
    }
    __syncthreads();
    int lane = t & 63, mm = lane & 15, quad = lane >> 4;
    bf16x8 af0 = *(const bf16x8*)&INF[((wv * 4 + quad) * 16 + mm) * 8];
    // P = W0r @ feat (no bias/relu)
    {
        f32x4 acc[8] = {};
        #pragma unroll
        for (int nt = 0; nt < 8; nt++) {
            bf16x8 bf = *(const bf16x8*)(w0r + (size_t)(nt * 16 + mm) * 32 + quad * 8);
            acc[nt] = MFMA(af0, bf, acc[nt]);
        }
        #pragma unroll
        for (int nt = 0; nt < 8; nt++) {
            int col = nt * 16 + mm;
            #pragma unroll
            for (int rg = 0; rg < 4; rg++) {
                int row = wv * 16 + quad * 4 + rg;
                P[(size_t)(base + row) * 128 + col] = f2b(acc[nt][rg]);
            }
        }
    }
    // Q = W0s @ feat
    {
        f32x4 acc[8] = {};
        #pragma unroll
        for (int nt = 0; nt < 8; nt++) {
            bf16x8 bf = *(const bf16x8*)(w0s + (size_t)(nt * 16 + mm) * 32 + quad * 8);
            acc[nt] = MFMA(af0, bf, acc[nt]);
        }
        #pragma unroll
        for (int nt = 0; nt < 8; nt++) {
            int col = nt * 16 + mm;
            #pragma unroll
            for (int rg = 0; rg < 4; rg++) {
                int row = wv * 16 + quad * 4 + rg;
                Q[(size_t)(base + row) * 128 + col] = f2b(acc[nt][rg]);
            }
        }
    }
    // pe layer1 -> BUFB (frag layout)
    {
        f32x4 acc[8] = {};
        #pragma unroll
        for (int nt = 0; nt < 8; nt++) {
            bf16x8 bf = *(const bf16x8*)(pew0 + (size_t)(nt * 16 + mm) * 32 + quad * 8);
            acc[nt] = MFMA(af0, bf, acc[nt]);
        }
        #pragma unroll
        for (int nt = 0; nt < 8; nt++) {
            int col = nt * 16 + mm;
            #pragma unroll
            for (int rg = 0; rg < 4; rg++) {
                BUFB[((wv * 16 + (col >> 3)) * 16 + quad * 4 + rg) * 8 + (col & 7)] =
                    f2b(fmaxf(acc[nt][rg] + b0_s[col], 0.f));
            }
        }
    }
    __syncthreads();
    // pe layer2 (K=128) -> BUFA (frag)
    {
        f32x4 acc[8] = {};
        for (int kc = 0; kc < 4; kc++) {
            bf16x8 af = *(const bf16x8*)&BUFB[((wv * 16 + kc * 4 + quad) * 16 + mm) * 8];
            #pragma unroll
            for (int nt = 0; nt < 8; nt++) {
                bf16x8 bf = *(const bf16x8*)(pew1 + (size_t)(nt * 16 + mm) * 128 + kc * 32 + quad * 8);
                acc[nt] = MFMA(af, bf, acc[nt]);
            }
        }
        __syncthreads();
        #pragma unroll
        for (int nt = 0; nt < 8; nt++) {
            int col = nt * 16 + mm;
            #pragma unroll
            for (int rg = 0; rg < 4; rg++) {
                BUFA[((wv * 16 + (col >> 3)) * 16 + quad * 4 + rg) * 8 + (col & 7)] =
                    f2b(fmaxf(acc[nt][rg] + b1_s[col], 0.f));
            }
        }
    }
    __syncthreads();
    // T = Wp @ particle_encode (no bias/relu)
    {
        f32x4 acc[8] = {};
        for (int kc = 0; kc < 4; kc++) {
            bf16x8 af = *(const bf16x8*)&BUFA[((wv * 16 + kc * 4 + quad) * 16 + mm) * 8];
            #pragma unroll
            for (int nt = 0; nt < 8; nt++) {
                bf16x8 bf = *(const bf16x8*)(wp + (size_t)(nt * 16 + mm) * 128 + kc * 32 + quad * 8);
                acc[nt] = MFMA(af, bf, acc[nt]);
            }
        }
        #pragma unroll
        for (int nt = 0; nt < 8; nt++) {
            int col = nt * 16 + mm;
            #pragma unroll
            for (int rg = 0; rg < 4; rg++) {
                int row = wv * 16 + quad * 4 + rg;
                T[(size_t)(base + row) * 128 + col] = f2b(acc[nt][rg]);
            }
        }
    }
}

// ================= relation: gather-add -> L2 -> L3 -> Z; fused step1 segsum =================
__global__ __launch_bounds__(256) void k_rel(
        const u16* __restrict__ P, const u16* __restrict__ Q,
        const float* __restrict__ Ra, const u32* __restrict__ perm,
        const int* __restrict__ srecv, const int* __restrict__ ssend,
        const float* __restrict__ re_w0_raw, const float* __restrict__ b0,
        const u16* __restrict__ w1b, const float* __restrict__ b1,
        const u16* __restrict__ w2b, const float* __restrict__ b2,
        const u16* __restrict__ wreb, const float* __restrict__ rpb,
        u16* __restrict__ Z, float* __restrict__ agg) {
    __shared__ __align__(16) char SMEM[64 * 132 * 4];   // 33792 B
    u16* BUFA = (u16*)SMEM;
    u16* BUFB = (u16*)(SMEM + 16384);
    float* S = (float*)SMEM;
    __shared__ int rv_s[64], sv_s[64];
    __shared__ float wRa_s[128], b0_s[128], b1_s[128], b2_s[128], rpb_s[128];
    int t = threadIdx.x;
    long base = (long)blockIdx.x * 64;
    if (t < 64) { rv_s[t] = srecv[base + t]; sv_s[t] = ssend[base + t]; }
    if (t < 128) {
        wRa_s[t] = re_w0_raw[t * 31 + 30];
        b0_s[t] = b0[t]; b1_s[t] = b1[t]; b2_s[t] = b2[t]; rpb_s[t] = rpb[t];
    }
    __syncthreads();
    int wv = t >> 6, kq4 = (t >> 4) & 3, m = t & 15;
    int lane = t & 63, mm = lane & 15, quad = lane >> 4;
    // stage H1 = relu(P[rv] + Q[sv] + Ra*wRa + b0) into BUFA (frag layout)
    {
        int e = wv * 16 + m;
        int rvp = rv_s[e], svp = sv_s[e];
        float ra = Ra[perm[base + e]];
        #pragma unroll
        for (int i = 0; i < 4; i++) {
            int kq = kq4 + 4 * i;
            uint4 up = *(const uint4*)(P + (size_t)rvp * 128 + kq * 8);
            uint4 uq = *(const uint4*)(Q + (size_t)svp * 128 + kq * 8);
            const u16* pp = (const u16*)&up; const u16* qq = (const u16*)&uq;
            u16 outv[8];
            #pragma unroll
            for (int j = 0; j < 8; j++) {
                int c = kq * 8 + j;
                float v = b2f(pp[j]) + b2f(qq[j]) + ra * wRa_s[c] + b0_s[c];
                outv[j] = f2b(fmaxf(v, 0.f));
            }
            *(uint4*)&BUFA[((wv * 16 + kq) * 16 + m) * 8] = *(uint4*)outv;
        }
    }
    __syncthreads();
    // layer2: BUFA -> BUFB
    {
        f32x4 acc[8] = {};
        for (int kc = 0; kc < 4; kc++) {
            bf16x8 af = *(const bf16x8*)&BUFA[((wv * 16 + kc * 4 + quad) * 16 + mm) * 8];
            #pragma unroll
            for (int nt = 0; nt < 8; nt++) {
                bf16x8 bf = *(const bf16x8*)(w1b + (size_t)(nt * 16 + mm) * 128 + kc * 32 + quad * 8);
                acc[nt] = MFMA(af, bf, acc[nt]);
            }
        }
        __syncthreads();
        #pragma unroll
        for (int nt = 0; nt < 8; nt++) {
            int col = nt * 16 + mm;
            #pragma unroll
            for (int rg = 0; rg < 4; rg++) {
                BUFB[((wv * 16 + (col >> 3)) * 16 + quad * 4 + rg) * 8 + (col & 7)] =
                    f2b(fmaxf(acc[nt][rg] + b1_s[col], 0.f));
            }
        }
    }
    __syncthreads();
    // layer3: BUFB -> BUFA
    {
        f32x4 acc[8] = {};
        for (int kc = 0; kc < 4; kc++) {
            bf16x8 af = *(const bf16x8*)&BUFB[((wv * 16 + kc * 4 + quad) * 16 + mm) * 8];
            #pragma unroll
            for (int nt = 0; nt < 8; nt++) {
                bf16x8 bf = *(const bf16x8*)(w2b + (size_t)(nt * 16 + mm) * 128 + kc * 32 + quad * 8);
                acc[nt] = MFMA(af, bf, acc[nt]);
            }
        }
        __syncthreads();
        #pragma unroll
        for (int nt = 0; nt < 8; nt++) {
            int col = nt * 16 + mm;
            #pragma unroll
            for (int rg = 0; rg < 4; rg++) {
                BUFA[((wv * 16 + (col >> 3)) * 16 + quad * 4 + rg) * 8 + (col & 7)] =
                    f2b(fmaxf(acc[nt][rg] + b2_s[col], 0.f));
            }
        }
    }
    __syncthreads();
    // layer4: Z = Wre @ relation_encode (regs), write Z global
    f32x4 zacc[8] = {};
    for (int kc = 0; kc < 4; kc++) {
        bf16x8 af = *(const bf16x8*)&BUFA[((wv * 16 + kc * 4 + quad) * 16 + mm) * 8];
        #pragma unroll
        for (int nt = 0; nt < 8; nt++) {
            bf16x8 bf = *(const bf16x8*)(wreb + (size_t)(nt * 16 + mm) * 128 + kc * 32 + quad * 8);
            zacc[nt] = MFMA(af, bf, zacc[nt]);
        }
    }
    #pragma unroll
    for (int nt = 0; nt < 8; nt++) {
        int col = nt * 16 + mm;
        #pragma unroll
        for (int rg = 0; rg < 4; rg++) {
            long row = base + wv * 16 + quad * 4 + rg;
            Z[row * 128 + col] = f2b(zacc[nt][rg]);
        }
    }
    __syncthreads();   // all BUF reads done -> S overlay is safe
    // step-1 rel_eff = relu(Z + rp_b) into S
    #pragma unroll
    for (int nt = 0; nt < 8; nt++) {
        int col = nt * 16 + mm;
        #pragma unroll
        for (int rg = 0; rg < 4; rg++) {
            int row = wv * 16 + quad * 4 + rg;
            S[row * 132 + col] = fmaxf(zacc[nt][rg] + rpb_s[col], 0.f);
        }
    }
    __syncthreads();
    // run-length segmented sum over sorted recv
    {
        int s = t >> 7, col = t & 127;
        int r0 = s * 32;
        int cur = rv_s[r0];
        float a = S[r0 * 132 + col];
        for (int rr = r0 + 1; rr < r0 + 32; rr++) {
            int n = rv_s[rr];
            float v = S[rr * 132 + col];
            if (n == cur) a += v;
            else { atomicAdd(&agg[(size_t)cur * 128 + col], a); cur = n; a = v; }
        }
        atomicAdd(&agg[(size_t)cur * 128 + col], a);
    }
}

// ================= node update: eff = relu(Wa@agg + T + pp_b) =================
__global__ __launch_bounds__(256) void k_node2(
        const float* __restrict__ agg, const u16* __restrict__ T,
        const u16* __restrict__ wab, const float* __restrict__ ppb,
        u16* __restrict__ effb) {
    __shared__ u16 AF[64 * 128];
    __shared__ float ppb_s[128];
    int t = threadIdx.x;
    long base = (long)blockIdx.x * 64;
    if (t < 128) ppb_s[t] = ppb[t];
    int wv = t >> 6, kq4 = (t >> 4) & 3, m = t & 15;
    {
        long node = base + wv * 16 + m;
        #pragma unroll
        for (int i = 0; i < 4; i++) {
            int kq = kq4 + 4 * i;
            const float* src = agg + node * 128 + kq * 8;
            float4 f0 = *(const float4*)src, f1 = *(const float4*)(src + 4);
            uint4 v;
            v.x = pk2(f0.x, f0.y); v.y = pk2(f0.z, f0.w);
            v.z = pk2(f1.x, f1.y); v.w = pk2(f1.z, f1.w);
            *(uint4*)&AF[((wv * 16 + kq) * 16 + m) * 8] = v;
        }
    }
    __syncthreads();
    int lane = t & 63, mm = lane & 15, quad = lane >> 4;
    f32x4 acc[8] = {};
    for (int kc = 0; kc < 4; kc++) {
        bf16x8 af = *(const bf16x8*)&AF[((wv * 16 + kc * 4 + quad) * 16 + mm) * 8];
        #pragma unroll
        for (int nt = 0; nt < 8; nt++) {
            bf16x8 bf = *(const bf16x8*)(wab + (size_t)(nt * 16 + mm) * 128 + kc * 32 + quad * 8);
            acc[nt] = MFMA(af, bf, acc[nt]);
        }
    }
    #pragma unroll
    for (int nt = 0; nt < 8; nt++) {
        int col = nt * 16 + mm;
        #pragma unroll
        for (int rg = 0; rg < 4; rg++) {
            long row = base + wv * 16 + quad * 4 + rg;
            float v = acc[nt][rg] + b2f(T[row * 128 + col]) + ppb_s[col];
            effb[row * 128 + col] = f2b(fmaxf(v, 0.f));
        }
    }
}

// ================= U = Wr@eff, V = Ws@eff =================
__global__ __launch_bounds__(256) void k_uv(
        const u16* __restrict__ effb,
        const u16* __restrict__ wrb, const u16* __restrict__ wsb,
        u16* __restrict__ U, u16* __restrict__ V) {
    __shared__ u16 AF[64 * 128];
    int t = threadIdx.x;
    long base = (long)blockIdx.x * 64;
    int wv = t >> 6, kq4 = (t >> 4) & 3, m = t & 15;
    {
        long node = base + wv * 16 + m;
        #pragma unroll
        for (int i = 0; i < 4; i++) {
            int kq = kq4 + 4 * i;
            *(uint4*)&AF[((wv * 16 + kq) * 16 + m) * 8] =
                *(const uint4*)(effb + node * 128 + kq * 8);
        }
    }
    __syncthreads();
    int lane = t & 63, mm = lane & 15, quad = lane >> 4;
    f32x4 accU[8] = {}, accV[8] = {};
    for (int kc = 0; kc < 4; kc++) {
        bf16x8 af = *(const bf16x8*)&AF[((wv * 16 + kc * 4 + quad) * 16 + mm) * 8];
        #pragma unroll
        for (int nt = 0; nt < 8; nt++) {
            bf16x8 bu = *(const bf16x8*)(wrb + (size_t)(nt * 16 + mm) * 128 + kc * 32 + quad * 8);
            bf16x8 bv = *(const bf16x8*)(wsb + (size_t)(nt * 16 + mm) * 128 + kc * 32 + quad * 8);
            accU[nt] = MFMA(af, bu, accU[nt]);
            accV[nt] = MFMA(af, bv, accV[nt]);
        }
    }
    #pragma unroll
    for (int nt = 0; nt < 8; nt++) {
        int col = nt * 16 + mm;
        #pragma unroll
        for (int rg = 0; rg < 4; rg++) {
            long row = base + wv * 16 + quad * 4 + rg;
            U[row * 128 + col] = f2b(accU[nt][rg]);
            V[row * 128 + col] = f2b(accV[nt][rg]);
        }
    }
}

// ================= step-2 edge: relu(Z + U[rv] + V[sv] + b) -> segsum =================
__global__ __launch_bounds__(256) void k_edge2(
        const u16* __restrict__ Z, const u16* __restrict__ U, const u16* __restrict__ V,
        const int* __restrict__ srecv, const int* __restrict__ ssend,
        const float* __restrict__ rpb, float* __restrict__ agg) {
    __shared__ float S[64 * 132];
    __shared__ int rv_s[64], sv_s[64];
    __shared__ float rpb_s[128];
    int t = threadIdx.x;
    long base = (long)blockIdx.x * 64;
    if (t < 64) { rv_s[t] = srecv[base + t]; sv_s[t] = ssend[base + t]; }
    if (t < 128) rpb_s[t] = rpb[t];
    __syncthreads();
    int r = t >> 2, q = t & 3;
    long zb = (base + r) * 128;
    long ub = (size_t)rv_s[r] * 128, vb = (size_t)sv_s[r] * 128;
    #pragma unroll
    for (int i = 0; i < 4; i++) {
        int c0 = q * 32 + i * 8;
        uint4 uz = *(const uint4*)(Z + zb + c0);
        uint4 uu = *(const uint4*)(U + ub + c0);
        uint4 uv = *(const uint4*)(V + vb + c0);
        const u16* zz = (const u16*)&uz; const u16* pu = (const u16*)&uu; const u16* pv = (const u16*)&uv;
        float o[8];
        #pragma unroll
        for (int j = 0; j < 8; j++)
            o[j] = fmaxf(b2f(zz[j]) + b2f(pu[j]) + b2f(pv[j]) + rpb_s[c0 + j], 0.f);
        *(float4*)&S[r * 132 + c0]     = *(float4*)&o[0];
        *(float4*)&S[r * 132 + c0 + 4] = *(float4*)&o[4];
    }
    __syncthreads();
    {
        int s = t >> 7, col = t & 127;
        int r0 = s * 32;
        int cur = rv_s[r0];
        float a = S[r0 * 132 + col];
        for (int rr = r0 + 1; rr < r0 + 32; rr++) {
            int n = rv_s[rr];
            float v = S[rr * 132 + col];
            if (n == cur) a += v;
            else { atomicAdd(&agg[(size_t)cur * 128 + col], a); cur = n; a = v; }
        }
        atomicAdd(&agg[(size_t)cur * 128 + col], a);
    }
}

// ================= pooled mean over effect[:RIG] =================
__global__ __launch_bounds__(256) void k_pool(const u16* __restrict__ effb,
                                              float* __restrict__ pooled) {
    int f = blockIdx.x;
    __shared__ float red[256];
    float s = 0.f;
    for (int r = threadIdx.x; r < RIG_; r += 256) s += b2f(effb[(size_t)r * 128 + f]);
    red[threadIdx.x] = s; __syncthreads();
    for (int o = 128; o > 0; o >>= 1) {
        if (threadIdx.x < o) red[threadIdx.x] += red[threadIdx.x + o];
        __syncthreads();
    }
    if (threadIdx.x == 0) pooled[f] = red[0] / (float)RIG_;
}

// ================= rigid head =================
__global__ __launch_bounds__(128) void k_rigid_head(
        const float* __restrict__ pooled,
        const float* __restrict__ w0, const float* __restrict__ b0,
        const float* __restrict__ w1, const float* __restrict__ b1,
        const float* __restrict__ w2, const float* __restrict__ b2,
        float* __restrict__ rig) {
    __shared__ float pl[128], ha[128], hb[128], tv[7];
    int t = threadIdx.x;
    pl[t] = pooled[t];
    __syncthreads();
    float a = b0[t];
    for (int k = 0; k < 128; k++) a += w0[t * 128 + k] * pl[k];
    ha[t] = fmaxf(a, 0.f);
    __syncthreads();
    a = b1[t];
    for (int k = 0; k < 128; k++) a += w1[t * 128 + k] * ha[k];
    hb[t] = fmaxf(a, 0.f);
    __syncthreads();
    if (t < 7) {
        float s = b2[t];
        for (int k = 0; k < 128; k++) s += w2[t * 128 + k] * hb[k];
        tv[t] = s;
    }
    __syncthreads();
    if (t == 0) {
        float w = tv[0], x = tv[1], y = tv[2], z = tv[3];
        float n = sqrtf(w * w + x * x + y * y + z * z);
        w /= n; x /= n; y /= n; z /= n;
        rig[0] = 1.f - 2.f * (y * y + z * z); rig[1] = 2.f * (x * y + z * w); rig[2] = 2.f * (x * z - y * w);
        rig[3] = 2.f * (x * y - z * w); rig[4] = 1.f - 2.f * (x * x + z * z); rig[5] = 2.f * (y * z + x * w);
        rig[6] = 2.f * (x * z + y * w); rig[7] = 2.f * (y * z - x * w); rig[8] = 1.f - 2.f * (x * x + y * y);
        rig[9] = tv[4]; rig[10] = tv[5]; rig[11] = tv[6];
    }
}

// ================= rigid output =================
__global__ __launch_bounds__(256) void k_rigid_out(
        const float* __restrict__ state, const float* __restrict__ cent,
        const float* __restrict__ rig, float* __restrict__ out) {
    int i = blockIdx.x * 256 + threadIdx.x;
    if (i >= RIG_) return;
    float p0[3], d[3];
    #pragma unroll
    for (int k = 0; k < 3; k++) { p0[k] = state[i * 6 + k]; d[k] = p0[k] - cent[k]; }
    #pragma unroll
    for (int j = 0; j < 3; j++) {
        float p1 = rig[0 * 3 + j] * d[0] + rig[1 * 3 + j] * d[1] + rig[2 * 3 + j] * d[2]
                 + rig[9 + j] + cent[j];
        out[i * 3 + j] = (p1 - p0[j]) * 60.0f;
    }
}

// ================= fluid MFMA: 128 -> 128 -> 128 -> 3(pad16) =================
#define HPAD 136
__global__ __launch_bounds__(256) void k_fluid(
        const u16* __restrict__ effb,
        const u16* __restrict__ w0b, const float* __restrict__ b0,
        const u16* __restrict__ w1b, const float* __restrict__ b1,
        const u16* __restrict__ w2b, const float* __restrict__ b2,
        float* __restrict__ out) {
    __shared__ u16 H0[64 * HPAD];
    __shared__ u16 H1[64 * HPAD];
    int t = threadIdx.x;
    long base = RIG_ + (long)blockIdx.x * 64;
    int r = t >> 2, q = t & 3;
    {
        const u16* src = effb + (base + r) * 128 + q * 32;
        u16* dst = &H0[r * HPAD + q * 32];
        #pragma unroll
        for (int i = 0; i < 32; i += 8)
            *(uint4*)(dst + i) = *(const uint4*)(src + i);
    }
    __syncthreads();
    int wv = t >> 6, lane = t & 63;
    int m = lane & 15, quad = lane >> 4;
    {
        f32x4 acc[8] = {};
        for (int kc = 0; kc < 4; kc++) {
            bf16x8 af = *(const bf16x8*)&H0[(wv * 16 + m) * HPAD + kc * 32 + quad * 8];
            #pragma unroll
            for (int nt = 0; nt < 8; nt++) {
                bf16x8 bf = *(const bf16x8*)(w0b + (size_t)(nt * 16 + m) * 128 + kc * 32 + quad * 8);
                acc[nt] = MFMA(af, bf, acc[nt]);
            }
        }
        #pragma unroll
        for (int nt = 0; nt < 8; nt++) {
            int col = nt * 16 + m;
            float bv = b0[col];
            #pragma unroll
            for (int rg = 0; rg < 4; rg++) {
                int row = wv * 16 + quad * 4 + rg;
                H1[row * HPAD + col] = f2b(fmaxf(acc[nt][rg] + bv, 0.f));
            }
        }
    }
    __syncthreads();
    {
        f32x4 acc[8] = {};
        for (int kc = 0; kc < 4; kc++) {
            bf16x8 af = *(const bf16x8*)&H1[(wv * 16 + m) * HPAD + kc * 32 + quad * 8];
            #pragma unroll
            for (int nt = 0; nt < 8; nt++) {
                bf16x8 bf = *(const bf16x8*)(w1b + (size_t)(nt * 16 + m) * 128 + kc * 32 + quad * 8);
                acc[nt] = MFMA(af, bf, acc[nt]);
            }
        }
        __syncthreads();
        #pragma unroll
        for (int nt = 0; nt < 8; nt++) {
            int col = nt * 16 + m;
            float bv = b1[col];
            #pragma unroll
            for (int rg = 0; rg < 4; rg++) {
                int row = wv * 16 + quad * 4 + rg;
                H0[row * HPAD + col] = f2b(fmaxf(acc[nt][rg] + bv, 0.f));
            }
        }
    }
    __syncthreads();
    {
        f32x4 acc = {};
        for (int kc = 0; kc < 4; kc++) {
            bf16x8 af = *(const bf16x8*)&H0[(wv * 16 + m) * HPAD + kc * 32 + quad * 8];
            bf16x8 bf = *(const bf16x8*)(w2b + (size_t)m * 128 + kc * 32 + quad * 8);
            acc = MFMA(af, bf, acc);
        }
        if (m < 3) {
            float bv = b2[m];
            #pragma unroll
            for (int rg = 0; rg < 4; rg++) {
                long row = base + wv * 16 + quad * 4 + rg;
                out[row * 3 + m] = acc[rg] + bv;
            }
        }
    }
}

// ================= host =================
extern "C" void kernel_launch(void* const* d_in, const int* in_sizes, int n_in,
                              void* d_out, int out_size, void* d_ws, size_t ws_size,
                              hipStream_t stream) {
    const float* state = (const float*)d_in[0];
    const float* attr  = (const float*)d_in[1];
    const float* Ra    = (const float*)d_in[2];
    const int*   recv  = (const int*)d_in[3];
    const int*   send  = (const int*)d_in[4];
    const float* pe_w0 = (const float*)d_in[5];  const float* pe_b0 = (const float*)d_in[6];
    const float* pe_w1 = (const float*)d_in[7];  const float* pe_b1 = (const float*)d_in[8];
    const float* re_w0 = (const float*)d_in[9];  const float* re_b0 = (const float*)d_in[10];
    const float* re_w1 = (const float*)d_in[11]; const float* re_b1 = (const float*)d_in[12];
    const float* re_w2 = (const float*)d_in[13]; const float* re_b2 = (const float*)d_in[14];
    const float* rp_w  = (const float*)d_in[15]; const float* rp_b  = (const float*)d_in[16];
    const float* pp_w  = (const float*)d_in[17]; const float* pp_b  = (const float*)d_in[18];
    const float* rg_w0 = (const float*)d_in[19]; const float* rg_b0 = (const float*)d_in[20];
    const float* rg_w1 = (const float*)d_in[21]; const float* rg_b1 = (const float*)d_in[22];
    const float* rg_w2 = (const float*)d_in[23]; const float* rg_b2 = (const float*)d_in[24];
    const float* fl_w0 = (const float*)d_in[25]; const float* fl_b0 = (const float*)d_in[26];
    const float* fl_w1 = (const float*)d_in[27]; const float* fl_b1 = (const float*)d_in[28];
    const float* fl_w2 = (const float*)d_in[29]; const float* fl_b2 = (const float*)d_in[30];
    float* out = (float*)d_out;

    // ---- workspace carve-out ----
    char* p = (char*)d_ws;
    auto alloc = [&](size_t bytes) { char* r = p; p += (bytes + 255) / 256 * 256; return r; };
    float* cent    = (float*)alloc(8 * 4);
    float* pooled  = (float*)alloc(128 * 4);
    float* rig     = (float*)alloc(16 * 4);
    u32*   rowhead = (u32*)alloc((size_t)N_P * 4);
    u32*   bsum    = (u32*)alloc(256 * 4);
    u32*   perm    = (u32*)alloc((size_t)N_E * 4);
    int*   srecv   = (int*)alloc((size_t)N_E * 4);
    int*   ssend   = (int*)alloc((size_t)N_E * 4);
    float* agg     = (float*)alloc((size_t)N_P * 128 * 4);
    u16*   Z       = (u16*)alloc((size_t)N_E * 128 * 2);
    u16*   effb    = (u16*)alloc((size_t)N_P * 128 * 2);
    u16*   T       = (u16*)alloc((size_t)N_P * 128 * 2);
    u16*   P       = (u16*)alloc((size_t)N_P * 128 * 2);   // aliased as U after k_rel
    u16*   Q       = (u16*)alloc((size_t)N_P * 128 * 2);   // aliased as V after k_rel
    u16*   wreb    = (u16*)alloc(128 * 128 * 2);
    u16*   wrb     = (u16*)alloc(128 * 128 * 2);
    u16*   wsb     = (u16*)alloc(128 * 128 * 2);
    u16*   wpb     = (u16*)alloc(128 * 128 * 2);
    u16*   wab     = (u16*)alloc(128 * 128 * 2);
    u16*   rw1b    = (u16*)alloc(128 * 128 * 2);
    u16*   rw2b    = (u16*)alloc(128 * 128 * 2);
    u16*   pew1b   = (u16*)alloc(128 * 128 * 2);
    u16*   flw0b   = (u16*)alloc(128 * 128 * 2);
    u16*   flw1b   = (u16*)alloc(128 * 128 * 2);
    u16*   flw2b   = (u16*)alloc(16 * 128 * 2);
    u16*   w0rb    = (u16*)alloc(128 * 32 * 2);
    u16*   w0sb    = (u16*)alloc(128 * 32 * 2);
    u16*   pew0b   = (u16*)alloc(128 * 32 * 2);
    size_t need = (size_t)(p - (char*)d_ws);
    if (ws_size < need) {
        fprintf(stderr, "kernel_launch: ws_size %zu < needed %zu\n", ws_size, need);
        return;
    }
    u16* U = P; u16* V = Q;

    // ---- sort edges by recv ----
    hipMemsetAsync(rowhead, 0, (size_t)N_P * 4, stream);
    k_hist<<<N_E / 256, 256, 0, stream>>>(recv, rowhead);
    k_scan1<<<N_P / 256, 256, 0, stream>>>(rowhead, bsum);
    k_scan2<<<1, 256, 0, stream>>>(bsum);
    k_scan3<<<N_P / 256, 256, 0, stream>>>(rowhead, bsum);
    k_scatter<<<N_E / 256, 256, 0, stream>>>(recv, send, rowhead, perm, srecv, ssend);

    // ---- weight conversion ----
    CvtArgs ca;
    int bs = 0;
    auto addjob = [&](int idx, const float* s, u16* d, int n, int mode) {
        ca.j[idx] = {s, d, n, mode, bs};
        bs += (n + 255) / 256;
    };
    addjob(0,  rp_w,        wreb,  128 * 128, 3);
    addjob(1,  rp_w + 128,  wrb,   128 * 128, 3);
    addjob(2,  rp_w + 256,  wsb,   128 * 128, 3);
    addjob(3,  pp_w,        wpb,   128 * 128, 4);
    addjob(4,  pp_w + 128,  wab,   128 * 128, 4);
    addjob(5,  re_w1,       rw1b,  128 * 128, 0);
    addjob(6,  re_w2,       rw2b,  128 * 128, 0);
    addjob(7,  pe_w1,       pew1b, 128 * 128, 0);
    addjob(8,  fl_w0,       flw0b, 128 * 128, 0);
    addjob(9,  fl_w1,       flw1b, 128 * 128, 0);
    addjob(10, fl_w2,       flw2b, 16 * 128,  2);
    addjob(11, re_w0,       w0rb,  128 * 32,  5);
    addjob(12, re_w0,       w0sb,  128 * 32,  6);
    addjob(13, pe_w0,       pew0b, 128 * 32,  7);
    k_cvt_all<<<bs, 256, 0, stream>>>(ca);

    // ---- encoders ----
    k_centroid<<<6, 256, 0, stream>>>(state, cent);
    k_particle_ext<<<N_P / 64, 256, 0, stream>>>(state, attr, cent,
                                                 w0rb, w0sb, pew0b, pe_b0,
                                                 pew1b, pe_b1, wpb, P, Q, T);

    // ---- step 1: rel-enc + Z + fused agg ----
    hipMemsetAsync(agg, 0, (size_t)N_P * 128 * 4, stream);
    k_rel<<<N_E / 64, 256, 0, stream>>>(P, Q, Ra, perm, srecv, ssend,
                                        re_w0, re_b0, rw1b, re_b1, rw2b, re_b2,
                                        wreb, rp_b, Z, agg);
    k_node2<<<N_P / 64, 256, 0, stream>>>(agg, T, wab, pp_b, effb);

    // ---- step 2 ----
    k_uv<<<N_P / 64, 256, 0, stream>>>(effb, wrb, wsb, U, V);
    hipMemsetAsync(agg, 0, (size_t)N_P * 128 * 4, stream);
    k_edge2<<<N_E / 64, 256, 0, stream>>>(Z, U, V, srecv, ssend, rp_b, agg);
    k_node2<<<N_P / 64, 256, 0, stream>>>(agg, T, wab, pp_b, effb);

    // ---- heads ----
    k_pool<<<128, 256, 0, stream>>>(effb, pooled);
    k_rigid_head<<<1, 128, 0, stream>>>(pooled, rg_w0, rg_b0, rg_w1, rg_b1, rg_w2, rg_b2, rig);
    k_rigid_out<<<(RIG_ + 255) / 256, 256, 0, stream>>>(state, cent, rig, out);
    k_fluid<<<(N_P - RIG_) / 64, 256, 0, stream>>>(effb, flw0b, fl_b0, flw1b, fl_b1,
                                                   flw2b, fl_b2, out);
}